// Round 8
// baseline (1399.271 us; speedup 1.0000x reference)
//
#include <hip/hip_runtime.h>
#include <hip/hip_bf16.h>
#include <math.h>

// Problem constants
#define N_ 8
#define S_ 1024
#define F_ 64
#define E_ 512
#define H_ 8
#define O_ 64
#define L_ 6
#define HD_ 64
#define FF_ 2048
#define SCALE_ 0.044194173824159216f   // 1/sqrt(E) -- module scales by sqrt(embed_size)
#define LOG2E_ 1.4426950408889634f
#define QSCALE_ (SCALE_ * LOG2E_)      // folded into Q at projection time

typedef unsigned short u16;
typedef __attribute__((ext_vector_type(8))) unsigned short u16x8;
typedef __attribute__((ext_vector_type(8))) short short8;
typedef __attribute__((ext_vector_type(4))) float floatx4;

__device__ __forceinline__ u16 f2b(float f) {          // RNE (weights, one-time)
    union { float f; unsigned u; } v; v.f = f;
    unsigned u = v.u;
    unsigned r = (u + 0x7FFFu + ((u >> 16) & 1u)) >> 16;
    return (u16)r;
}
__device__ __forceinline__ u16 f2b_fast(float f) {     // round-nearest, 2 ops
    union { float f; unsigned u; } v; v.f = f;
    return (u16)((v.u + 0x8000u) >> 16);
}
// bijection on [0,16): spreads C-layout rows (4*quad+r) across all 32 banks
__device__ __forceinline__ int pperm(int row) {
    return ((2 * (row >> 2) + 5 * (row & 3)) & 7) | ((row & 2) << 2);
}

// ---------------------------------------------------------------------------
// MFMA first projection: h[n,s,e] = relu(x^T W + b) + pos. A = x[n,:,s] (K=64).
__global__ __launch_bounds__(256) void first_mfma(
    const float* __restrict__ x, const u16* __restrict__ wt,
    const float* __restrict__ bf, const float* __restrict__ pe,
    float* __restrict__ hout, u16* __restrict__ hb)
{
    __shared__ u16 a_s[128][72];
    int t = threadIdx.x;
    int w = t >> 6, lane = t & 63, quad = lane >> 4, c16 = lane & 15;
    int rowhalf = w >> 1, colhalf = w & 1;
    int col0 = blockIdx.x * 128;
    int row0 = blockIdx.y * 128;          // n*S + s0 (never crosses n: 1024%128==0)
    int n = row0 >> 10, s0 = row0 & 1023;

    const float* xb = x + (size_t)n * F_ * S_ + s0;
    #pragma unroll
    for (int i = 0; i < 8; i++) {
        int pos = (t + i * 256) * 4;      // 8192 elems, f-major
        int f = pos >> 7, sl = pos & 127;
        float4 v = *(const float4*)&xb[(size_t)f * S_ + sl];
        a_s[sl + 0][f] = f2b_fast(v.x);
        a_s[sl + 1][f] = f2b_fast(v.y);
        a_s[sl + 2][f] = f2b_fast(v.z);
        a_s[sl + 3][f] = f2b_fast(v.w);
    }
    __syncthreads();

    floatx4 acc[4][4];
    #pragma unroll
    for (int mt = 0; mt < 4; mt++)
        #pragma unroll
        for (int nt = 0; nt < 4; nt++) acc[mt][nt] = (floatx4){0.f, 0.f, 0.f, 0.f};

    #pragma unroll
    for (int ks = 0; ks < 2; ks++) {
        short8 af[4], bfr[4];
        #pragma unroll
        for (int mt = 0; mt < 4; mt++)
            af[mt] = *(const short8*)&a_s[rowhalf * 64 + mt * 16 + c16][ks * 32 + quad * 8];
        #pragma unroll
        for (int nt = 0; nt < 4; nt++)
            bfr[nt] = *(const short8*)&wt[(size_t)(col0 + colhalf * 64 + nt * 16 + c16) * F_
                                          + ks * 32 + quad * 8];
        #pragma unroll
        for (int mt = 0; mt < 4; mt++)
            #pragma unroll
            for (int nt = 0; nt < 4; nt++)
                acc[mt][nt] = __builtin_amdgcn_mfma_f32_16x16x32_bf16(
                    af[mt], bfr[nt], acc[mt][nt], 0, 0, 0);
    }

    #pragma unroll
    for (int nt = 0; nt < 4; nt++) {
        int col = col0 + colhalf * 64 + nt * 16 + c16;
        float bv = bf[col];
        #pragma unroll
        for (int mt = 0; mt < 4; mt++) {
            #pragma unroll
            for (int r = 0; r < 4; r++) {
                size_t row = (size_t)row0 + rowhalf * 64 + mt * 16 + quad * 4 + r;
                int s = (int)(row & 1023);
                float v = fmaxf(acc[mt][nt][r] + bv, 0.f) + pe[(size_t)s * E_ + col];
                hout[row * E_ + col] = v;
                hb[row * E_ + col] = f2b_fast(v);
            }
        }
    }
}

// ---------------------------------------------------------------------------
// batched cast+transpose: W[K][Nc] fp32 -> Wt[Nc][K] bf16, per-layer stride.
__global__ __launch_bounds__(256) void wcast_t(
    const float* __restrict__ W0, u16* __restrict__ Wt0, int K, int Nc)
{
    __shared__ float tile[32][33];
    int t = threadIdx.x;
    int bx = blockIdx.x, by = blockIdx.y;
    const float* W = W0 + (size_t)blockIdx.z * K * Nc;
    u16* Wt = Wt0 + (size_t)blockIdx.z * K * Nc;
    #pragma unroll
    for (int i = 0; i < 4; i++) {
        int q = t + i * 256; int r = q >> 5, c = q & 31;
        tile[r][c] = W[(size_t)(by * 32 + r) * Nc + bx * 32 + c];
    }
    __syncthreads();
    #pragma unroll
    for (int i = 0; i < 4; i++) {
        int q = t + i * 256; int r = q >> 5, c = q & 31;
        Wt[(size_t)(bx * 32 + r) * K + by * 32 + c] = f2b(tile[c][r]);
    }
}

// ---------------------------------------------------------------------------
// batched cast+transpose of the three 64x64 qkv weights; block = layer
__global__ __launch_bounds__(256) void qkvw_cast(
    const float* __restrict__ Wq, const float* __restrict__ Wk,
    const float* __restrict__ Wv,
    u16* __restrict__ wqt, u16* __restrict__ wkt, u16* __restrict__ wvt)
{
    int l = blockIdx.x;
    int t = threadIdx.x;
    size_t off = (size_t)l * HD_ * HD_;
    #pragma unroll
    for (int i = 0; i < 16; i++) {
        int idx = t + i * 256;            // = e*64 + d
        int e = idx >> 6, d = idx & 63;
        wqt[off + idx] = f2b(Wq[off + d * HD_ + e]);
        wkt[off + idx] = f2b(Wk[off + d * HD_ + e]);
        wvt[off + idx] = f2b(Wv[off + d * HD_ + e]);
    }
}

// ---------------------------------------------------------------------------
// MFMA fused qkv; Q output pre-scaled by QSCALE_ (folded softmax scale+log2e)
__global__ __launch_bounds__(256) void qkv_mfma(
    const u16* __restrict__ hb,
    const u16* __restrict__ wqt, const u16* __restrict__ wkt,
    const u16* __restrict__ wvt,
    const float* __restrict__ bq, const float* __restrict__ bk,
    const float* __restrict__ bv,
    u16* __restrict__ qo, u16* __restrict__ ko, u16* __restrict__ vo)
{
    __shared__ u16 a_s[256][72];
    int t = threadIdx.x;
    int w = t >> 6, lane = t & 63, quad = lane >> 4, c16 = lane & 15;
    size_t row0 = (size_t)blockIdx.x * 256;

    #pragma unroll
    for (int i = 0; i < 8; i++) {
        int q = t + i * 256; int r = q >> 3, c = q & 7;
        *(u16x8*)&a_s[r][c * 8] = *(const u16x8*)&hb[(row0 + r) * HD_ + c * 8];
    }
    __syncthreads();

    short8 af[4][2];
    #pragma unroll
    for (int mt = 0; mt < 4; mt++)
        #pragma unroll
        for (int ks = 0; ks < 2; ks++)
            af[mt][ks] = *(const short8*)&a_s[w * 64 + mt * 16 + c16][ks * 32 + quad * 8];

    const u16* wts[3] = {wqt, wkt, wvt};
    const float* bs[3] = {bq, bk, bv};
    u16* outs[3] = {qo, ko, vo};

    #pragma unroll
    for (int m = 0; m < 3; m++) {
        short8 bfr[4][2];
        #pragma unroll
        for (int nt = 0; nt < 4; nt++)
            #pragma unroll
            for (int ks = 0; ks < 2; ks++)
                bfr[nt][ks] = *(const short8*)&wts[m][(nt * 16 + c16) * HD_ + ks * 32 + quad * 8];
        floatx4 acc[4][4];
        #pragma unroll
        for (int mt = 0; mt < 4; mt++)
            #pragma unroll
            for (int nt = 0; nt < 4; nt++) acc[mt][nt] = (floatx4){0.f, 0.f, 0.f, 0.f};
        #pragma unroll
        for (int ks = 0; ks < 2; ks++)
            #pragma unroll
            for (int mt = 0; mt < 4; mt++)
                #pragma unroll
                for (int nt = 0; nt < 4; nt++)
                    acc[mt][nt] = __builtin_amdgcn_mfma_f32_16x16x32_bf16(
                        af[mt][ks], bfr[nt][ks], acc[mt][nt], 0, 0, 0);
        float osc = (m == 0) ? QSCALE_ : 1.0f;
        #pragma unroll
        for (int nt = 0; nt < 4; nt++) {
            float bv_ = bs[m][nt * 16 + c16];
            #pragma unroll
            for (int mt = 0; mt < 4; mt++)
                #pragma unroll
                for (int r = 0; r < 4; r++)
                    outs[m][(row0 + w * 64 + mt * 16 + quad * 4 + r) * HD_ + nt * 16 + c16] =
                        f2b_fast((acc[mt][nt][r] + bv_) * osc);
        }
    }
}

// ---------------------------------------------------------------------------
// V transpose: vb (N,S,H,D) bf16 -> vt (N,H,D,S) bf16. grid N*H*(S/64)
__global__ __launch_bounds__(256) void vtrans(
    const u16* __restrict__ vb, u16* __restrict__ vt)
{
    int bid = blockIdx.x;
    int st = bid & 15, hh = (bid >> 4) & 7, n = bid >> 7;
    __shared__ u16 tile[64][72];
    int t = threadIdx.x;
    #pragma unroll
    for (int i = 0; i < 2; i++) {
        int q = t + i * 256; int sl = q >> 3, c = q & 7;
        *(u16x8*)&tile[sl][c * 8] =
            *(const u16x8*)&vb[(((size_t)(n * S_ + st * 64 + sl)) * H_ + hh) * 64 + c * 8];
    }
    __syncthreads();
    #pragma unroll
    for (int i = 0; i < 2; i++) {
        int q = t + i * 256; int d = q >> 3, sc = q & 7;
        u16x8 v;
        #pragma unroll
        for (int j = 0; j < 8; j++) v[j] = tile[sc * 8 + j][d];
        *(u16x8*)&vt[((size_t)(n * H_ + hh) * 64 + d) * (size_t)S_ + st * 64 + sc * 8] = v;
    }
}

// ---------------------------------------------------------------------------
// MFMA flash attention, no-max exp2 softmax (Q pre-scaled by QSCALE_).
// Block = (n, h, 128-query tile), 256 thr = 4 waves; wave handles 32 q-rows.
// LDS: P strips aliased onto the Q tile (Q read once into registers) -> 37 KB
// -> 4 blocks/CU. K/V prefetch issued after mid-barrier (in flight over MFMA).
__global__ __launch_bounds__(256, 4) void attn_mfma(
    const u16* __restrict__ Q, const u16* __restrict__ K,
    const u16* __restrict__ Vt, u16* __restrict__ O)
{
    int bid = blockIdx.x;            // N*H*(S/128) = 512
    int qt = bid & 7, hh = (bid >> 3) & 7, n = bid >> 6;
    int t = threadIdx.x;
    int w = t >> 6, lane = t & 63, quad = lane >> 4, c16 = lane & 15;

    __shared__ u16 qp_s[128][72];    // Q tile, then per-wave P strips
    __shared__ u16 k_s[64][72];
    __shared__ u16 vt_s[64][72];
    u16 (*p_s)[72] = &qp_s[w * 32];  // wave-private 32-row strip

    const size_t qkbase = (size_t)n * S_ * E_ + hh * 64;
    const size_t vtbase = ((size_t)(n * H_ + hh) * 64) * (size_t)S_;

    #pragma unroll
    for (int i = 0; i < 4; i++) {
        int q = t + i * 256; int r = q >> 3, c = q & 7;
        *(u16x8*)&qp_s[r][c * 8] =
            *(const u16x8*)&Q[qkbase + (size_t)(qt * 128 + r) * E_ + c * 8];
    }
    __syncthreads();

    short8 af[2][2];
    #pragma unroll
    for (int mt = 0; mt < 2; mt++)
        #pragma unroll
        for (int ks = 0; ks < 2; ks++)
            af[mt][ks] = *(const short8*)&qp_s[w * 32 + mt * 16 + c16][ks * 32 + quad * 8];

    const short8 ones = {(short)0x3F80, (short)0x3F80, (short)0x3F80, (short)0x3F80,
                         (short)0x3F80, (short)0x3F80, (short)0x3F80, (short)0x3F80};
    const int pr = pperm(c16);
    int pw[4];
    #pragma unroll
    for (int r = 0; r < 4; r++) pw[r] = pperm(quad * 4 + r);

    floatx4 oacc[2][4], lacc[2];
    #pragma unroll
    for (int mt = 0; mt < 2; mt++) {
        lacc[mt] = (floatx4){0.f, 0.f, 0.f, 0.f};
        #pragma unroll
        for (int nt = 0; nt < 4; nt++) oacc[mt][nt] = (floatx4){0.f, 0.f, 0.f, 0.f};
    }

    // register prefetch of K/V tiles
    int ar = t >> 3, acq = (t & 7) * 8;
    u16x8 pk[2], pv[2];
    #pragma unroll
    for (int i = 0; i < 2; i++) {
        pk[i] = *(const u16x8*)&K[qkbase + (size_t)(ar + i * 32) * E_ + acq];
        pv[i] = *(const u16x8*)&Vt[vtbase + (size_t)(ar + i * 32) * S_ + acq];
    }
    // note: the hoist of af above happens before the first in-loop barrier,
    // so overwriting qp_s (P strips) after that barrier is safe.

    for (int k0 = 0; k0 < S_; k0 += 64) {
        #pragma unroll
        for (int i = 0; i < 2; i++) {
            *(u16x8*)&k_s[ar + i * 32][acq] = pk[i];
            *(u16x8*)&vt_s[ar + i * 32][acq] = pv[i];
        }
        __syncthreads();
        // prefetch next tile AFTER the barrier: loads stay in flight across
        // the whole MFMA/softmax section, drained only at the end barrier.
        if (k0 + 64 < S_) {
            #pragma unroll
            for (int i = 0; i < 2; i++) {
                pk[i] = *(const u16x8*)&K[qkbase + (size_t)(k0 + 64 + ar + i * 32) * E_ + acq];
                pv[i] = *(const u16x8*)&Vt[vtbase + (size_t)(ar + i * 32) * S_ + k0 + 64 + acq];
            }
        }

        floatx4 sc[2][4];
        #pragma unroll
        for (int mt = 0; mt < 2; mt++)
            #pragma unroll
            for (int nt = 0; nt < 4; nt++) sc[mt][nt] = (floatx4){0.f, 0.f, 0.f, 0.f};
        #pragma unroll
        for (int ks = 0; ks < 2; ks++) {
            short8 bfr[4];
            #pragma unroll
            for (int nt = 0; nt < 4; nt++)
                bfr[nt] = *(const short8*)&k_s[nt * 16 + c16][ks * 32 + quad * 8];
            #pragma unroll
            for (int mt = 0; mt < 2; mt++)
                #pragma unroll
                for (int nt = 0; nt < 4; nt++)
                    sc[mt][nt] = __builtin_amdgcn_mfma_f32_16x16x32_bf16(
                        af[mt][ks], bfr[nt], sc[mt][nt], 0, 0, 0);
        }

        #pragma unroll
        for (int mt = 0; mt < 2; mt++)
            #pragma unroll
            for (int nt = 0; nt < 4; nt++)
                #pragma unroll
                for (int r = 0; r < 4; r++)
                    p_s[mt * 16 + pw[r]][nt * 16 + c16] =
                        f2b_fast(exp2f(sc[mt][nt][r]));

        #pragma unroll
        for (int ks = 0; ks < 2; ks++) {
            short8 vf[4];
            #pragma unroll
            for (int nt = 0; nt < 4; nt++)
                vf[nt] = *(const short8*)&vt_s[nt * 16 + c16][ks * 32 + quad * 8];
            #pragma unroll
            for (int mt = 0; mt < 2; mt++) {
                short8 pf = *(const short8*)&p_s[mt * 16 + pr][ks * 32 + quad * 8];
                lacc[mt] = __builtin_amdgcn_mfma_f32_16x16x32_bf16(pf, ones, lacc[mt], 0, 0, 0);
                #pragma unroll
                for (int nt = 0; nt < 4; nt++)
                    oacc[mt][nt] = __builtin_amdgcn_mfma_f32_16x16x32_bf16(
                        pf, vf[nt], oacc[mt][nt], 0, 0, 0);
            }
        }
        __syncthreads();
    }

    #pragma unroll
    for (int mt = 0; mt < 2; mt++)
        #pragma unroll
        for (int r = 0; r < 4; r++) {
            float rl = 1.f / lacc[mt][r];
            int s = qt * 128 + w * 32 + mt * 16 + quad * 4 + r;
            size_t base = (size_t)(n * S_ + s) * E_ + hh * 64;
            #pragma unroll
            for (int nt = 0; nt < 4; nt++)
                O[base + nt * 16 + c16] = f2b_fast(oacc[mt][nt][r] * rl);
        }
}

// ---------------------------------------------------------------------------
// MFMA GEMM, software-pipelined staging: prefetch issued after the mid
// barrier so loads are in flight across the MFMA section.
// Tile = MT x 128 (MT in {64,128}), 4 waves: 2 row-halves x 2 col-halves.
template <int MT, bool RELU, bool HASRES, bool OUTF32, bool OUTBF16>
__global__ __launch_bounds__(256, 4) void gemm_mfma(
    const u16* __restrict__ A, const u16* __restrict__ Bt,
    const float* __restrict__ bias, const float* __restrict__ resid,
    float* __restrict__ outf, u16* __restrict__ outb, int M, int Nc, int K)
{
    constexpr int MTILES = MT / 32;          // m-tiles per wave; also A staging passes
    __shared__ u16 a_s[MT][72];
    __shared__ u16 b_s[128][72];
    int t = threadIdx.x;
    int w = t >> 6, lane = t & 63, quad = lane >> 4, c16 = lane & 15;
    int rowhalf = w >> 1, colhalf = w & 1;
    size_t row0 = (size_t)blockIdx.y * MT;
    size_t col0 = (size_t)blockIdx.x * 128;

    floatx4 acc[MTILES][4];
    #pragma unroll
    for (int mt = 0; mt < MTILES; mt++)
        #pragma unroll
        for (int nt = 0; nt < 4; nt++) acc[mt][nt] = (floatx4){0.f, 0.f, 0.f, 0.f};

    int ar = t >> 3, acq = (t & 7) * 8;      // staging row (0..31) / col
    u16x8 pa[MTILES], pb[4];
    #pragma unroll
    for (int i = 0; i < MTILES; i++)
        pa[i] = *(const u16x8*)&A[(row0 + ar + i * 32) * K + acq];
    #pragma unroll
    for (int i = 0; i < 4; i++)
        pb[i] = *(const u16x8*)&Bt[(col0 + ar + i * 32) * K + acq];

    for (int k0 = 0; k0 < K; k0 += 64) {
        #pragma unroll
        for (int i = 0; i < MTILES; i++)
            *(u16x8*)&a_s[ar + i * 32][acq] = pa[i];
        #pragma unroll
        for (int i = 0; i < 4; i++)
            *(u16x8*)&b_s[ar + i * 32][acq] = pb[i];
        __syncthreads();
        if (k0 + 64 < K) {
            #pragma unroll
            for (int i = 0; i < MTILES; i++)
                pa[i] = *(const u16x8*)&A[(row0 + ar + i * 32) * K + k0 + 64 + acq];
            #pragma unroll
            for (int i = 0; i < 4; i++)
                pb[i] = *(const u16x8*)&Bt[(col0 + ar + i * 32) * K + k0 + 64 + acq];
        }
        #pragma unroll
        for (int ks = 0; ks < 2; ks++) {
            short8 af[MTILES], bf[4];
            #pragma unroll
            for (int mt = 0; mt < MTILES; mt++)
                af[mt] = *(const short8*)&a_s[rowhalf * (MT / 2) + mt * 16 + c16][ks * 32 + quad * 8];
            #pragma unroll
            for (int nt = 0; nt < 4; nt++)
                bf[nt] = *(const short8*)&b_s[colhalf * 64 + nt * 16 + c16][ks * 32 + quad * 8];
            #pragma unroll
            for (int mt = 0; mt < MTILES; mt++)
                #pragma unroll
                for (int nt = 0; nt < 4; nt++)
                    acc[mt][nt] = __builtin_amdgcn_mfma_f32_16x16x32_bf16(
                        af[mt], bf[nt], acc[mt][nt], 0, 0, 0);
        }
        __syncthreads();
    }

    #pragma unroll
    for (int nt = 0; nt < 4; nt++) {
        int col = (int)col0 + colhalf * 64 + nt * 16 + c16;
        float bv = bias[col];
        #pragma unroll
        for (int mt = 0; mt < MTILES; mt++) {
            size_t rowb = row0 + rowhalf * (MT / 2) + mt * 16 + quad * 4;
            #pragma unroll
            for (int r = 0; r < 4; r++) {
                size_t row = rowb + r;
                float v = acc[mt][nt][r] + bv;
                if constexpr (HASRES) v += resid[row * Nc + col];
                if constexpr (RELU) v = fmaxf(v, 0.f);
                if constexpr (OUTF32) outf[row * Nc + col] = v;
                if constexpr (OUTBF16) outb[row * Nc + col] = f2b_fast(v);
            }
        }
    }
}

// ---------------------------------------------------------------------------
// LayerNorm over E=512, one block per row; optional bf16 copy
template <bool EMITB>
__global__ __launch_bounds__(256) void layernorm_k(
    const float* __restrict__ in, const float* __restrict__ g,
    const float* __restrict__ bb, float* __restrict__ out, u16* __restrict__ outb)
{
    int row = blockIdx.x;
    int t = threadIdx.x;
    const float* x = in + (size_t)row * E_;
    float x0 = x[t], x1 = x[t + 256];
    float s = x0 + x1;
    #pragma unroll
    for (int off = 32; off; off >>= 1) s += __shfl_down(s, off, 64);
    __shared__ float red[4];
    int wid = t >> 6, lane = t & 63;
    if (lane == 0) red[wid] = s;
    __syncthreads();
    float m = (red[0] + red[1] + red[2] + red[3]) * (1.f / E_);
    float d0 = x0 - m, d1 = x1 - m;
    float sq = d0 * d0 + d1 * d1;
    #pragma unroll
    for (int off = 32; off; off >>= 1) sq += __shfl_down(sq, off, 64);
    __syncthreads();
    if (lane == 0) red[wid] = sq;
    __syncthreads();
    float var = (red[0] + red[1] + red[2] + red[3]) * (1.f / E_);
    float rstd = rsqrtf(var + 1e-5f);
    float o0 = d0 * rstd * g[t] + bb[t];
    float o1 = d1 * rstd * g[t + 256] + bb[t + 256];
    out[(size_t)row * E_ + t] = o0;
    out[(size_t)row * E_ + t + 256] = o1;
    if constexpr (EMITB) {
        outb[(size_t)row * E_ + t] = f2b_fast(o0);
        outb[(size_t)row * E_ + t + 256] = f2b_fast(o1);
    }
}

// ---------------------------------------------------------------------------
// MFMA final projection: out[n,o,s] = hb[n*S+s,:] @ Wfint[o,:] + bfin[o]
__global__ __launch_bounds__(256) void final_mfma(
    const u16* __restrict__ hb, const u16* __restrict__ wft,
    const float* __restrict__ bfin, float* __restrict__ outp)
{
    __shared__ u16 a_s[64][72];
    int t = threadIdx.x;
    int w = t >> 6, lane = t & 63, quad = lane >> 4, c16 = lane & 15;
    size_t row0 = (size_t)blockIdx.x * 64;

    floatx4 acc[4];
    #pragma unroll
    for (int nt = 0; nt < 4; nt++) acc[nt] = (floatx4){0.f, 0.f, 0.f, 0.f};

    int ar = t >> 3, acq = (t & 7) * 8;
    u16x8 pa[2];
    #pragma unroll
    for (int i = 0; i < 2; i++)
        pa[i] = *(const u16x8*)&hb[(row0 + ar + i * 32) * E_ + acq];

    for (int k0 = 0; k0 < E_; k0 += 64) {
        #pragma unroll
        for (int i = 0; i < 2; i++)
            *(u16x8*)&a_s[ar + i * 32][acq] = pa[i];
        __syncthreads();
        if (k0 + 64 < E_) {
            #pragma unroll
            for (int i = 0; i < 2; i++)
                pa[i] = *(const u16x8*)&hb[(row0 + ar + i * 32) * E_ + k0 + 64 + acq];
        }
        #pragma unroll
        for (int ks = 0; ks < 2; ks++) {
            short8 af = *(const short8*)&a_s[w * 16 + c16][ks * 32 + quad * 8];
            #pragma unroll
            for (int nt = 0; nt < 4; nt++) {
                short8 bf = *(const short8*)&wft[(nt * 16 + c16) * E_ + k0 + ks * 32 + quad * 8];
                acc[nt] = __builtin_amdgcn_mfma_f32_16x16x32_bf16(af, bf, acc[nt], 0, 0, 0);
            }
        }
        __syncthreads();
    }

    #pragma unroll
    for (int nt = 0; nt < 4; nt++) {
        int o = nt * 16 + c16;
        float bv = bfin[o];
        #pragma unroll
        for (int r = 0; r < 4; r++) {
            size_t row = row0 + w * 16 + quad * 4 + r;    // n*S + s
            int n = (int)(row >> 10), s = (int)(row & 1023);
            outp[((size_t)(n * O_ + o)) * S_ + s] = acc[nt][r] + bv;
        }
    }
}

// ---------------------------------------------------------------------------
extern "C" void kernel_launch(void* const* d_in, const int* in_sizes, int n_in,
                              void* d_out, int out_size, void* d_ws, size_t ws_size,
                              hipStream_t stream)
{
    const float* x       = (const float*)d_in[0];
    const float* W_first = (const float*)d_in[1];
    const float* b_first = (const float*)d_in[2];
    const float* pos_emb = (const float*)d_in[3];
    const float* Wq      = (const float*)d_in[4];
    const float* bq      = (const float*)d_in[5];
    const float* Wk      = (const float*)d_in[6];
    const float* bk      = (const float*)d_in[7];
    const float* Wv      = (const float*)d_in[8];
    const float* bv      = (const float*)d_in[9];
    const float* Wo      = (const float*)d_in[10];
    const float* bo      = (const float*)d_in[11];
    const float* g1      = (const float*)d_in[12];
    const float* be1     = (const float*)d_in[13];
    const float* Wf1     = (const float*)d_in[14];
    const float* bf1     = (const float*)d_in[15];
    const float* Wf2     = (const float*)d_in[16];
    const float* bf2     = (const float*)d_in[17];
    const float* g2      = (const float*)d_in[18];
    const float* be2     = (const float*)d_in[19];
    const float* Wfin    = (const float*)d_in[20];
    const float* bfin    = (const float*)d_in[21];
    float* out = (float*)d_out;

    const size_t M4 = (size_t)N_ * S_ * E_;       // 4,194,304
    float* hbuf = (float*)d_ws;                   // fp32 activations
    float* t1   = hbuf + M4;
    float* hx   = t1 + M4;
    u16*   hxb  = (u16*)(hx + M4);                // bf16 LN1 out; ALSO bf16 h (hb)
    u16*   hb   = hxb;                            // alias: h consumed before LN1 writes
    u16*   qb   = hxb + M4;
    u16*   kb   = qb + M4;
    u16*   vb   = kb + M4;
    u16*   vt   = vb + M4;
    u16*   ob   = vt + M4;
    u16*   ffb  = qb;                             // alias qb..vt region
    u16*   wot  = ob + M4;                        // 6 * 512*512
    u16*   wf1t = wot + (size_t)L_ * E_ * E_;     // 6 * 2048*512 (as [FF][E])
    u16*   wf2t = wf1t + (size_t)L_ * E_ * FF_;   // 6 * 512*2048 (as [E][FF])
    u16*   wqt  = wf2t + (size_t)L_ * FF_ * E_;   // 6 * 64*64
    u16*   wkt  = wqt + (size_t)L_ * HD_ * HD_;
    u16*   wvt  = wkt + (size_t)L_ * HD_ * HD_;
    u16*   wft  = wvt + (size_t)L_ * HD_ * HD_;   // 64*512  (Wfin as [O][E])
    u16*   w1t  = wft + (size_t)O_ * E_;          // 512*64  (W_first as [E][F])

    const int rows = N_ * S_;                     // 8192

    qkvw_cast<<<L_, 256, 0, stream>>>(Wq, Wk, Wv, wqt, wkt, wvt);
    wcast_t<<<dim3(E_ / 32, F_ / 32, 1), 256, 0, stream>>>(W_first, w1t, F_, E_);
    wcast_t<<<dim3(E_ / 32, E_ / 32, L_), 256, 0, stream>>>(Wo, wot, E_, E_);
    wcast_t<<<dim3(FF_ / 32, E_ / 32, L_), 256, 0, stream>>>(Wf1, wf1t, E_, FF_);
    wcast_t<<<dim3(E_ / 32, FF_ / 32, L_), 256, 0, stream>>>(Wf2, wf2t, FF_, E_);
    wcast_t<<<dim3(O_ / 32, E_ / 32, 1), 256, 0, stream>>>(Wfin, wft, E_, O_);

    first_mfma<<<dim3(E_ / 128, rows / 128), 256, 0, stream>>>(
        x, w1t, b_first, pos_emb, hbuf, hb);

    for (int i = 0; i < L_; i++) {
        qkv_mfma<<<256, 256, 0, stream>>>(
            hb, wqt + (size_t)i * HD_ * HD_, wkt + (size_t)i * HD_ * HD_,
            wvt + (size_t)i * HD_ * HD_, bq + i * HD_, bk + i * HD_, bv + i * HD_,
            qb, kb, vb);
        vtrans<<<1024, 256, 0, stream>>>(vb, vt);
        attn_mfma<<<512, 256, 0, stream>>>(qb, kb, vt, ob);
        // t1 = ob @ Wo + bo + hbuf   (64-row tile -> 512 blocks)
        gemm_mfma<64, false, true, true, false><<<dim3(E_ / 128, rows / 64), 256, 0, stream>>>(
            ob, wot + (size_t)i * E_ * E_, bo + i * E_, hbuf, t1, nullptr, rows, E_, E_);
        layernorm_k<true><<<rows, 256, 0, stream>>>(t1, g1 + i * E_, be1 + i * E_, hx, hxb);
        // ffb = relu(hx @ Wf1 + bf1)   (128-row tile, grid 1024)
        gemm_mfma<128, true, false, false, true><<<dim3(FF_ / 128, rows / 128), 256, 0, stream>>>(
            hxb, wf1t + (size_t)i * E_ * FF_, bf1 + i * FF_, nullptr, nullptr, ffb,
            rows, FF_, E_);
        // t1 = ffb @ Wf2 + bf2 + hx   (64-row tile -> 512 blocks)
        gemm_mfma<64, false, true, true, false><<<dim3(E_ / 128, rows / 64), 256, 0, stream>>>(
            ffb, wf2t + (size_t)i * FF_ * E_, bf2 + i * E_, hx, t1, nullptr,
            rows, E_, FF_);
        layernorm_k<true><<<rows, 256, 0, stream>>>(t1, g2 + i * E_, be2 + i * E_, hbuf, hb);
    }

    final_mfma<<<rows / 64, 256, 0, stream>>>(hb, wft, bfin, out);
}

// Round 9
// 1044.177 us; speedup vs baseline: 1.3401x; 1.3401x over previous
//
#include <hip/hip_runtime.h>
#include <hip/hip_bf16.h>
#include <math.h>

// Problem constants
#define N_ 8
#define S_ 1024
#define F_ 64
#define E_ 512
#define H_ 8
#define O_ 64
#define L_ 6
#define HD_ 64
#define FF_ 2048
#define SCALE_ 0.044194173824159216f   // 1/sqrt(E) -- module scales by sqrt(embed_size)
#define LOG2E_ 1.4426950408889634f
#define QSCALE_ (SCALE_ * LOG2E_)      // folded into Q at projection time

typedef unsigned short u16;
typedef __attribute__((ext_vector_type(8))) unsigned short u16x8;
typedef __attribute__((ext_vector_type(8))) short short8;
typedef __attribute__((ext_vector_type(4))) float floatx4;

__device__ __forceinline__ u16 f2b(float f) {          // RNE (weights, one-time)
    union { float f; unsigned u; } v; v.f = f;
    unsigned u = v.u;
    unsigned r = (u + 0x7FFFu + ((u >> 16) & 1u)) >> 16;
    return (u16)r;
}
__device__ __forceinline__ u16 f2b_fast(float f) {     // round-nearest, 2 ops
    union { float f; unsigned u; } v; v.f = f;
    return (u16)((v.u + 0x8000u) >> 16);
}
// bijection on [0,16): spreads C-layout rows (4*quad+r) across all 32 banks
__device__ __forceinline__ int pperm(int row) {
    return ((2 * (row >> 2) + 5 * (row & 3)) & 7) | ((row & 2) << 2);
}

// ---------------------------------------------------------------------------
// MFMA first projection: h[n,s,e] = relu(x^T W + b) + pos. A = x[n,:,s] (K=64).
__global__ __launch_bounds__(256) void first_mfma(
    const float* __restrict__ x, const u16* __restrict__ wt,
    const float* __restrict__ bf, const float* __restrict__ pe,
    float* __restrict__ hout, u16* __restrict__ hb)
{
    __shared__ u16 a_s[128][72];
    int t = threadIdx.x;
    int w = t >> 6, lane = t & 63, quad = lane >> 4, c16 = lane & 15;
    int rowhalf = w >> 1, colhalf = w & 1;
    int col0 = blockIdx.x * 128;
    int row0 = blockIdx.y * 128;          // n*S + s0 (never crosses n: 1024%128==0)
    int n = row0 >> 10, s0 = row0 & 1023;

    const float* xb = x + (size_t)n * F_ * S_ + s0;
    #pragma unroll
    for (int i = 0; i < 8; i++) {
        int pos = (t + i * 256) * 4;      // 8192 elems, f-major
        int f = pos >> 7, sl = pos & 127;
        float4 v = *(const float4*)&xb[(size_t)f * S_ + sl];
        a_s[sl + 0][f] = f2b_fast(v.x);
        a_s[sl + 1][f] = f2b_fast(v.y);
        a_s[sl + 2][f] = f2b_fast(v.z);
        a_s[sl + 3][f] = f2b_fast(v.w);
    }
    __syncthreads();

    floatx4 acc[4][4];
    #pragma unroll
    for (int mt = 0; mt < 4; mt++)
        #pragma unroll
        for (int nt = 0; nt < 4; nt++) acc[mt][nt] = (floatx4){0.f, 0.f, 0.f, 0.f};

    #pragma unroll
    for (int ks = 0; ks < 2; ks++) {
        short8 af[4], bfr[4];
        #pragma unroll
        for (int mt = 0; mt < 4; mt++)
            af[mt] = *(const short8*)&a_s[rowhalf * 64 + mt * 16 + c16][ks * 32 + quad * 8];
        #pragma unroll
        for (int nt = 0; nt < 4; nt++)
            bfr[nt] = *(const short8*)&wt[(size_t)(col0 + colhalf * 64 + nt * 16 + c16) * F_
                                          + ks * 32 + quad * 8];
        #pragma unroll
        for (int mt = 0; mt < 4; mt++)
            #pragma unroll
            for (int nt = 0; nt < 4; nt++)
                acc[mt][nt] = __builtin_amdgcn_mfma_f32_16x16x32_bf16(
                    af[mt], bfr[nt], acc[mt][nt], 0, 0, 0);
    }

    #pragma unroll
    for (int nt = 0; nt < 4; nt++) {
        int col = col0 + colhalf * 64 + nt * 16 + c16;
        float bv = bf[col];
        #pragma unroll
        for (int mt = 0; mt < 4; mt++) {
            #pragma unroll
            for (int r = 0; r < 4; r++) {
                size_t row = (size_t)row0 + rowhalf * 64 + mt * 16 + quad * 4 + r;
                int s = (int)(row & 1023);
                float v = fmaxf(acc[mt][nt][r] + bv, 0.f) + pe[(size_t)s * E_ + col];
                hout[row * E_ + col] = v;
                hb[row * E_ + col] = f2b_fast(v);
            }
        }
    }
}

// ---------------------------------------------------------------------------
// batched cast+transpose: W[K][Nc] fp32 -> Wt[Nc][K] bf16, per-layer stride.
__global__ __launch_bounds__(256) void wcast_t(
    const float* __restrict__ W0, u16* __restrict__ Wt0, int K, int Nc)
{
    __shared__ float tile[32][33];
    int t = threadIdx.x;
    int bx = blockIdx.x, by = blockIdx.y;
    const float* W = W0 + (size_t)blockIdx.z * K * Nc;
    u16* Wt = Wt0 + (size_t)blockIdx.z * K * Nc;
    #pragma unroll
    for (int i = 0; i < 4; i++) {
        int q = t + i * 256; int r = q >> 5, c = q & 31;
        tile[r][c] = W[(size_t)(by * 32 + r) * Nc + bx * 32 + c];
    }
    __syncthreads();
    #pragma unroll
    for (int i = 0; i < 4; i++) {
        int q = t + i * 256; int r = q >> 5, c = q & 31;
        Wt[(size_t)(bx * 32 + r) * K + by * 32 + c] = f2b(tile[c][r]);
    }
}

// ---------------------------------------------------------------------------
// batched cast+transpose of the three 64x64 qkv weights; block = layer
__global__ __launch_bounds__(256) void qkvw_cast(
    const float* __restrict__ Wq, const float* __restrict__ Wk,
    const float* __restrict__ Wv,
    u16* __restrict__ wqt, u16* __restrict__ wkt, u16* __restrict__ wvt)
{
    int l = blockIdx.x;
    int t = threadIdx.x;
    size_t off = (size_t)l * HD_ * HD_;
    #pragma unroll
    for (int i = 0; i < 16; i++) {
        int idx = t + i * 256;            // = e*64 + d
        int e = idx >> 6, d = idx & 63;
        wqt[off + idx] = f2b(Wq[off + d * HD_ + e]);
        wkt[off + idx] = f2b(Wk[off + d * HD_ + e]);
        wvt[off + idx] = f2b(Wv[off + d * HD_ + e]);
    }
}

// ---------------------------------------------------------------------------
// MFMA fused qkv; Q output pre-scaled by QSCALE_ (folded softmax scale+log2e)
__global__ __launch_bounds__(256) void qkv_mfma(
    const u16* __restrict__ hb,
    const u16* __restrict__ wqt, const u16* __restrict__ wkt,
    const u16* __restrict__ wvt,
    const float* __restrict__ bq, const float* __restrict__ bk,
    const float* __restrict__ bv,
    u16* __restrict__ qo, u16* __restrict__ ko, u16* __restrict__ vo)
{
    __shared__ u16 a_s[256][72];
    int t = threadIdx.x;
    int w = t >> 6, lane = t & 63, quad = lane >> 4, c16 = lane & 15;
    size_t row0 = (size_t)blockIdx.x * 256;

    #pragma unroll
    for (int i = 0; i < 8; i++) {
        int q = t + i * 256; int r = q >> 3, c = q & 7;
        *(u16x8*)&a_s[r][c * 8] = *(const u16x8*)&hb[(row0 + r) * HD_ + c * 8];
    }
    __syncthreads();

    short8 af[4][2];
    #pragma unroll
    for (int mt = 0; mt < 4; mt++)
        #pragma unroll
        for (int ks = 0; ks < 2; ks++)
            af[mt][ks] = *(const short8*)&a_s[w * 64 + mt * 16 + c16][ks * 32 + quad * 8];

    const u16* wts[3] = {wqt, wkt, wvt};
    const float* bs[3] = {bq, bk, bv};
    u16* outs[3] = {qo, ko, vo};

    #pragma unroll
    for (int m = 0; m < 3; m++) {
        short8 bfr[4][2];
        #pragma unroll
        for (int nt = 0; nt < 4; nt++)
            #pragma unroll
            for (int ks = 0; ks < 2; ks++)
                bfr[nt][ks] = *(const short8*)&wts[m][(nt * 16 + c16) * HD_ + ks * 32 + quad * 8];
        floatx4 acc[4][4];
        #pragma unroll
        for (int mt = 0; mt < 4; mt++)
            #pragma unroll
            for (int nt = 0; nt < 4; nt++) acc[mt][nt] = (floatx4){0.f, 0.f, 0.f, 0.f};
        #pragma unroll
        for (int ks = 0; ks < 2; ks++)
            #pragma unroll
            for (int mt = 0; mt < 4; mt++)
                #pragma unroll
                for (int nt = 0; nt < 4; nt++)
                    acc[mt][nt] = __builtin_amdgcn_mfma_f32_16x16x32_bf16(
                        af[mt][ks], bfr[nt][ks], acc[mt][nt], 0, 0, 0);
        float osc = (m == 0) ? QSCALE_ : 1.0f;
        #pragma unroll
        for (int nt = 0; nt < 4; nt++) {
            float bv_ = bs[m][nt * 16 + c16];
            #pragma unroll
            for (int mt = 0; mt < 4; mt++)
                #pragma unroll
                for (int r = 0; r < 4; r++)
                    outs[m][(row0 + w * 64 + mt * 16 + quad * 4 + r) * HD_ + nt * 16 + c16] =
                        f2b_fast((acc[mt][nt][r] + bv_) * osc);
        }
    }
}

// ---------------------------------------------------------------------------
// V transpose: vb (N,S,H,D) bf16 -> vt (N,H,D,S) bf16. grid N*H*(S/64)
__global__ __launch_bounds__(256) void vtrans(
    const u16* __restrict__ vb, u16* __restrict__ vt)
{
    int bid = blockIdx.x;
    int st = bid & 15, hh = (bid >> 4) & 7, n = bid >> 7;
    __shared__ u16 tile[64][72];
    int t = threadIdx.x;
    #pragma unroll
    for (int i = 0; i < 2; i++) {
        int q = t + i * 256; int sl = q >> 3, c = q & 7;
        *(u16x8*)&tile[sl][c * 8] =
            *(const u16x8*)&vb[(((size_t)(n * S_ + st * 64 + sl)) * H_ + hh) * 64 + c * 8];
    }
    __syncthreads();
    #pragma unroll
    for (int i = 0; i < 2; i++) {
        int q = t + i * 256; int d = q >> 3, sc = q & 7;
        u16x8 v;
        #pragma unroll
        for (int j = 0; j < 8; j++) v[j] = tile[sc * 8 + j][d];
        *(u16x8*)&vt[((size_t)(n * H_ + hh) * 64 + d) * (size_t)S_ + st * 64 + sc * 8] = v;
    }
}

// ---------------------------------------------------------------------------
// MFMA flash attention, no-max exp2 softmax (Q pre-scaled by QSCALE_).
// Block = (n, h, 128-query tile), 256 thr = 4 waves; wave handles 32 q-rows.
// LDS: P strips aliased onto the Q tile (Q read once into registers) -> 37 KB.
// launch_bounds kept at (256,2): forcing 4 waves/EU capped VGPR at 64 and
// spilled 60 MB to scratch (R8 regression). Occupancy comes from LDS instead.
__global__ __launch_bounds__(256, 2) void attn_mfma(
    const u16* __restrict__ Q, const u16* __restrict__ K,
    const u16* __restrict__ Vt, u16* __restrict__ O)
{
    int bid = blockIdx.x;            // N*H*(S/128) = 512
    int qt = bid & 7, hh = (bid >> 3) & 7, n = bid >> 6;
    int t = threadIdx.x;
    int w = t >> 6, lane = t & 63, quad = lane >> 4, c16 = lane & 15;

    __shared__ u16 qp_s[128][72];    // Q tile, then per-wave P strips
    __shared__ u16 k_s[64][72];
    __shared__ u16 vt_s[64][72];
    u16 (*p_s)[72] = &qp_s[w * 32];  // wave-private 32-row strip

    const size_t qkbase = (size_t)n * S_ * E_ + hh * 64;
    const size_t vtbase = ((size_t)(n * H_ + hh) * 64) * (size_t)S_;

    #pragma unroll
    for (int i = 0; i < 4; i++) {
        int q = t + i * 256; int r = q >> 3, c = q & 7;
        *(u16x8*)&qp_s[r][c * 8] =
            *(const u16x8*)&Q[qkbase + (size_t)(qt * 128 + r) * E_ + c * 8];
    }
    __syncthreads();

    short8 af[2][2];
    #pragma unroll
    for (int mt = 0; mt < 2; mt++)
        #pragma unroll
        for (int ks = 0; ks < 2; ks++)
            af[mt][ks] = *(const short8*)&qp_s[w * 32 + mt * 16 + c16][ks * 32 + quad * 8];

    const short8 ones = {(short)0x3F80, (short)0x3F80, (short)0x3F80, (short)0x3F80,
                         (short)0x3F80, (short)0x3F80, (short)0x3F80, (short)0x3F80};
    const int pr = pperm(c16);
    int pw[4];
    #pragma unroll
    for (int r = 0; r < 4; r++) pw[r] = pperm(quad * 4 + r);

    floatx4 oacc[2][4], lacc[2];
    #pragma unroll
    for (int mt = 0; mt < 2; mt++) {
        lacc[mt] = (floatx4){0.f, 0.f, 0.f, 0.f};
        #pragma unroll
        for (int nt = 0; nt < 4; nt++) oacc[mt][nt] = (floatx4){0.f, 0.f, 0.f, 0.f};
    }

    // register prefetch of K/V tiles
    int ar = t >> 3, acq = (t & 7) * 8;
    u16x8 pk[2], pv[2];
    #pragma unroll
    for (int i = 0; i < 2; i++) {
        pk[i] = *(const u16x8*)&K[qkbase + (size_t)(ar + i * 32) * E_ + acq];
        pv[i] = *(const u16x8*)&Vt[vtbase + (size_t)(ar + i * 32) * S_ + acq];
    }

    for (int k0 = 0; k0 < S_; k0 += 64) {
        #pragma unroll
        for (int i = 0; i < 2; i++) {
            *(u16x8*)&k_s[ar + i * 32][acq] = pk[i];
            *(u16x8*)&vt_s[ar + i * 32][acq] = pv[i];
        }
        __syncthreads();
        // prefetch next tile AFTER the barrier: loads stay in flight across
        // the MFMA/softmax section, drained only at the end barrier.
        if (k0 + 64 < S_) {
            #pragma unroll
            for (int i = 0; i < 2; i++) {
                pk[i] = *(const u16x8*)&K[qkbase + (size_t)(k0 + 64 + ar + i * 32) * E_ + acq];
                pv[i] = *(const u16x8*)&Vt[vtbase + (size_t)(ar + i * 32) * S_ + k0 + 64 + acq];
            }
        }

        floatx4 sc[2][4];
        #pragma unroll
        for (int mt = 0; mt < 2; mt++)
            #pragma unroll
            for (int nt = 0; nt < 4; nt++) sc[mt][nt] = (floatx4){0.f, 0.f, 0.f, 0.f};
        #pragma unroll
        for (int ks = 0; ks < 2; ks++) {
            short8 bfr[4];
            #pragma unroll
            for (int nt = 0; nt < 4; nt++)
                bfr[nt] = *(const short8*)&k_s[nt * 16 + c16][ks * 32 + quad * 8];
            #pragma unroll
            for (int mt = 0; mt < 2; mt++)
                #pragma unroll
                for (int nt = 0; nt < 4; nt++)
                    sc[mt][nt] = __builtin_amdgcn_mfma_f32_16x16x32_bf16(
                        af[mt][ks], bfr[nt], sc[mt][nt], 0, 0, 0);
        }

        #pragma unroll
        for (int mt = 0; mt < 2; mt++)
            #pragma unroll
            for (int nt = 0; nt < 4; nt++)
                #pragma unroll
                for (int r = 0; r < 4; r++)
                    p_s[mt * 16 + pw[r]][nt * 16 + c16] =
                        f2b_fast(exp2f(sc[mt][nt][r]));

        #pragma unroll
        for (int ks = 0; ks < 2; ks++) {
            short8 vf[4];
            #pragma unroll
            for (int nt = 0; nt < 4; nt++)
                vf[nt] = *(const short8*)&vt_s[nt * 16 + c16][ks * 32 + quad * 8];
            #pragma unroll
            for (int mt = 0; mt < 2; mt++) {
                short8 pf = *(const short8*)&p_s[mt * 16 + pr][ks * 32 + quad * 8];
                lacc[mt] = __builtin_amdgcn_mfma_f32_16x16x32_bf16(pf, ones, lacc[mt], 0, 0, 0);
                #pragma unroll
                for (int nt = 0; nt < 4; nt++)
                    oacc[mt][nt] = __builtin_amdgcn_mfma_f32_16x16x32_bf16(
                        pf, vf[nt], oacc[mt][nt], 0, 0, 0);
            }
        }
        __syncthreads();
    }

    #pragma unroll
    for (int mt = 0; mt < 2; mt++)
        #pragma unroll
        for (int r = 0; r < 4; r++) {
            float rl = 1.f / lacc[mt][r];
            int s = qt * 128 + w * 32 + mt * 16 + quad * 4 + r;
            size_t base = (size_t)(n * S_ + s) * E_ + hh * 64;
            #pragma unroll
            for (int nt = 0; nt < 4; nt++)
                O[base + nt * 16 + c16] = f2b_fast(oacc[mt][nt][r] * rl);
        }
}

// ---------------------------------------------------------------------------
// MFMA GEMM, software-pipelined staging: prefetch issued after the mid
// barrier so loads are in flight across the MFMA section.
// launch_bounds (256,2): (256,4) caused scratch spills (R8).
template <int MT, bool RELU, bool HASRES, bool OUTF32, bool OUTBF16>
__global__ __launch_bounds__(256, 2) void gemm_mfma(
    const u16* __restrict__ A, const u16* __restrict__ Bt,
    const float* __restrict__ bias, const float* __restrict__ resid,
    float* __restrict__ outf, u16* __restrict__ outb, int M, int Nc, int K)
{
    constexpr int MTILES = MT / 32;          // m-tiles per wave; also A staging passes
    __shared__ u16 a_s[MT][72];
    __shared__ u16 b_s[128][72];
    int t = threadIdx.x;
    int w = t >> 6, lane = t & 63, quad = lane >> 4, c16 = lane & 15;
    int rowhalf = w >> 1, colhalf = w & 1;
    size_t row0 = (size_t)blockIdx.y * MT;
    size_t col0 = (size_t)blockIdx.x * 128;

    floatx4 acc[MTILES][4];
    #pragma unroll
    for (int mt = 0; mt < MTILES; mt++)
        #pragma unroll
        for (int nt = 0; nt < 4; nt++) acc[mt][nt] = (floatx4){0.f, 0.f, 0.f, 0.f};

    int ar = t >> 3, acq = (t & 7) * 8;      // staging row (0..31) / col
    u16x8 pa[MTILES], pb[4];
    #pragma unroll
    for (int i = 0; i < MTILES; i++)
        pa[i] = *(const u16x8*)&A[(row0 + ar + i * 32) * K + acq];
    #pragma unroll
    for (int i = 0; i < 4; i++)
        pb[i] = *(const u16x8*)&Bt[(col0 + ar + i * 32) * K + acq];

    for (int k0 = 0; k0 < K; k0 += 64) {
        #pragma unroll
        for (int i = 0; i < MTILES; i++)
            *(u16x8*)&a_s[ar + i * 32][acq] = pa[i];
        #pragma unroll
        for (int i = 0; i < 4; i++)
            *(u16x8*)&b_s[ar + i * 32][acq] = pb[i];
        __syncthreads();
        if (k0 + 64 < K) {
            #pragma unroll
            for (int i = 0; i < MTILES; i++)
                pa[i] = *(const u16x8*)&A[(row0 + ar + i * 32) * K + k0 + 64 + acq];
            #pragma unroll
            for (int i = 0; i < 4; i++)
                pb[i] = *(const u16x8*)&Bt[(col0 + ar + i * 32) * K + k0 + 64 + acq];
        }
        #pragma unroll
        for (int ks = 0; ks < 2; ks++) {
            short8 af[MTILES], bf[4];
            #pragma unroll
            for (int mt = 0; mt < MTILES; mt++)
                af[mt] = *(const short8*)&a_s[rowhalf * (MT / 2) + mt * 16 + c16][ks * 32 + quad * 8];
            #pragma unroll
            for (int nt = 0; nt < 4; nt++)
                bf[nt] = *(const short8*)&b_s[colhalf * 64 + nt * 16 + c16][ks * 32 + quad * 8];
            #pragma unroll
            for (int mt = 0; mt < MTILES; mt++)
                #pragma unroll
                for (int nt = 0; nt < 4; nt++)
                    acc[mt][nt] = __builtin_amdgcn_mfma_f32_16x16x32_bf16(
                        af[mt], bf[nt], acc[mt][nt], 0, 0, 0);
        }
        __syncthreads();
    }

    #pragma unroll
    for (int nt = 0; nt < 4; nt++) {
        int col = (int)col0 + colhalf * 64 + nt * 16 + c16;
        float bv = bias[col];
        #pragma unroll
        for (int mt = 0; mt < MTILES; mt++) {
            size_t rowb = row0 + rowhalf * (MT / 2) + mt * 16 + quad * 4;
            #pragma unroll
            for (int r = 0; r < 4; r++) {
                size_t row = rowb + r;
                float v = acc[mt][nt][r] + bv;
                if constexpr (HASRES) v += resid[row * Nc + col];
                if constexpr (RELU) v = fmaxf(v, 0.f);
                if constexpr (OUTF32) outf[row * Nc + col] = v;
                if constexpr (OUTBF16) outb[row * Nc + col] = f2b_fast(v);
            }
        }
    }
}

// ---------------------------------------------------------------------------
// LayerNorm over E=512, one block per row; optional bf16 copy
template <bool EMITB>
__global__ __launch_bounds__(256) void layernorm_k(
    const float* __restrict__ in, const float* __restrict__ g,
    const float* __restrict__ bb, float* __restrict__ out, u16* __restrict__ outb)
{
    int row = blockIdx.x;
    int t = threadIdx.x;
    const float* x = in + (size_t)row * E_;
    float x0 = x[t], x1 = x[t + 256];
    float s = x0 + x1;
    #pragma unroll
    for (int off = 32; off; off >>= 1) s += __shfl_down(s, off, 64);
    __shared__ float red[4];
    int wid = t >> 6, lane = t & 63;
    if (lane == 0) red[wid] = s;
    __syncthreads();
    float m = (red[0] + red[1] + red[2] + red[3]) * (1.f / E_);
    float d0 = x0 - m, d1 = x1 - m;
    float sq = d0 * d0 + d1 * d1;
    #pragma unroll
    for (int off = 32; off; off >>= 1) sq += __shfl_down(sq, off, 64);
    __syncthreads();
    if (lane == 0) red[wid] = sq;
    __syncthreads();
    float var = (red[0] + red[1] + red[2] + red[3]) * (1.f / E_);
    float rstd = rsqrtf(var + 1e-5f);
    float o0 = d0 * rstd * g[t] + bb[t];
    float o1 = d1 * rstd * g[t + 256] + bb[t + 256];
    out[(size_t)row * E_ + t] = o0;
    out[(size_t)row * E_ + t + 256] = o1;
    if constexpr (EMITB) {
        outb[(size_t)row * E_ + t] = f2b_fast(o0);
        outb[(size_t)row * E_ + t + 256] = f2b_fast(o1);
    }
}

// ---------------------------------------------------------------------------
// MFMA final projection: out[n,o,s] = hb[n*S+s,:] @ Wfint[o,:] + bfin[o]
__global__ __launch_bounds__(256) void final_mfma(
    const u16* __restrict__ hb, const u16* __restrict__ wft,
    const float* __restrict__ bfin, float* __restrict__ outp)
{
    __shared__ u16 a_s[64][72];
    int t = threadIdx.x;
    int w = t >> 6, lane = t & 63, quad = lane >> 4, c16 = lane & 15;
    size_t row0 = (size_t)blockIdx.x * 64;

    floatx4 acc[4];
    #pragma unroll
    for (int nt = 0; nt < 4; nt++) acc[nt] = (floatx4){0.f, 0.f, 0.f, 0.f};

    int ar = t >> 3, acq = (t & 7) * 8;
    u16x8 pa[2];
    #pragma unroll
    for (int i = 0; i < 2; i++)
        pa[i] = *(const u16x8*)&hb[(row0 + ar + i * 32) * E_ + acq];

    for (int k0 = 0; k0 < E_; k0 += 64) {
        #pragma unroll
        for (int i = 0; i < 2; i++)
            *(u16x8*)&a_s[ar + i * 32][acq] = pa[i];
        __syncthreads();
        if (k0 + 64 < E_) {
            #pragma unroll
            for (int i = 0; i < 2; i++)
                pa[i] = *(const u16x8*)&hb[(row0 + ar + i * 32) * E_ + k0 + 64 + acq];
        }
        #pragma unroll
        for (int ks = 0; ks < 2; ks++) {
            short8 af = *(const short8*)&a_s[w * 16 + c16][ks * 32 + quad * 8];
            #pragma unroll
            for (int nt = 0; nt < 4; nt++) {
                short8 bf = *(const short8*)&wft[(nt * 16 + c16) * E_ + k0 + ks * 32 + quad * 8];
                acc[nt] = __builtin_amdgcn_mfma_f32_16x16x32_bf16(af, bf, acc[nt], 0, 0, 0);
            }
        }
        __syncthreads();
    }

    #pragma unroll
    for (int nt = 0; nt < 4; nt++) {
        int o = nt * 16 + c16;
        float bv = bfin[o];
        #pragma unroll
        for (int r = 0; r < 4; r++) {
            size_t row = row0 + w * 16 + quad * 4 + r;    // n*S + s
            int n = (int)(row >> 10), s = (int)(row & 1023);
            outp[((size_t)(n * O_ + o)) * S_ + s] = acc[nt][r] + bv;
        }
    }
}

// ---------------------------------------------------------------------------
extern "C" void kernel_launch(void* const* d_in, const int* in_sizes, int n_in,
                              void* d_out, int out_size, void* d_ws, size_t ws_size,
                              hipStream_t stream)
{
    const float* x       = (const float*)d_in[0];
    const float* W_first = (const float*)d_in[1];
    const float* b_first = (const float*)d_in[2];
    const float* pos_emb = (const float*)d_in[3];
    const float* Wq      = (const float*)d_in[4];
    const float* bq      = (const float*)d_in[5];
    const float* Wk      = (const float*)d_in[6];
    const float* bk      = (const float*)d_in[7];
    const float* Wv      = (const float*)d_in[8];
    const float* bv      = (const float*)d_in[9];
    const float* Wo      = (const float*)d_in[10];
    const float* bo      = (const float*)d_in[11];
    const float* g1      = (const float*)d_in[12];
    const float* be1     = (const float*)d_in[13];
    const float* Wf1     = (const float*)d_in[14];
    const float* bf1     = (const float*)d_in[15];
    const float* Wf2     = (const float*)d_in[16];
    const float* bf2     = (const float*)d_in[17];
    const float* g2      = (const float*)d_in[18];
    const float* be2     = (const float*)d_in[19];
    const float* Wfin    = (const float*)d_in[20];
    const float* bfin    = (const float*)d_in[21];
    float* out = (float*)d_out;

    const size_t M4 = (size_t)N_ * S_ * E_;       // 4,194,304
    float* hbuf = (float*)d_ws;                   // fp32 activations
    float* t1   = hbuf + M4;
    float* hx   = t1 + M4;
    u16*   hxb  = (u16*)(hx + M4);                // bf16 LN1 out; ALSO bf16 h (hb)
    u16*   hb   = hxb;                            // alias: h consumed before LN1 writes
    u16*   qb   = hxb + M4;
    u16*   kb   = qb + M4;
    u16*   vb   = kb + M4;
    u16*   vt   = vb + M4;
    u16*   ob   = vt + M4;
    u16*   ffb  = qb;                             // alias qb..vt region
    u16*   wot  = ob + M4;                        // 6 * 512*512
    u16*   wf1t = wot + (size_t)L_ * E_ * E_;     // 6 * 2048*512 (as [FF][E])
    u16*   wf2t = wf1t + (size_t)L_ * E_ * FF_;   // 6 * 512*2048 (as [E][FF])
    u16*   wqt  = wf2t + (size_t)L_ * FF_ * E_;   // 6 * 64*64
    u16*   wkt  = wqt + (size_t)L_ * HD_ * HD_;
    u16*   wvt  = wkt + (size_t)L_ * HD_ * HD_;
    u16*   wft  = wvt + (size_t)L_ * HD_ * HD_;   // 64*512  (Wfin as [O][E])
    u16*   w1t  = wft + (size_t)O_ * E_;          // 512*64  (W_first as [E][F])

    const int rows = N_ * S_;                     // 8192

    qkvw_cast<<<L_, 256, 0, stream>>>(Wq, Wk, Wv, wqt, wkt, wvt);
    wcast_t<<<dim3(E_ / 32, F_ / 32, 1), 256, 0, stream>>>(W_first, w1t, F_, E_);
    wcast_t<<<dim3(E_ / 32, E_ / 32, L_), 256, 0, stream>>>(Wo, wot, E_, E_);
    wcast_t<<<dim3(FF_ / 32, E_ / 32, L_), 256, 0, stream>>>(Wf1, wf1t, E_, FF_);
    wcast_t<<<dim3(E_ / 32, FF_ / 32, L_), 256, 0, stream>>>(Wf2, wf2t, FF_, E_);
    wcast_t<<<dim3(O_ / 32, E_ / 32, 1), 256, 0, stream>>>(Wfin, wft, E_, O_);

    first_mfma<<<dim3(E_ / 128, rows / 128), 256, 0, stream>>>(
        x, w1t, b_first, pos_emb, hbuf, hb);

    for (int i = 0; i < L_; i++) {
        qkv_mfma<<<256, 256, 0, stream>>>(
            hb, wqt + (size_t)i * HD_ * HD_, wkt + (size_t)i * HD_ * HD_,
            wvt + (size_t)i * HD_ * HD_, bq + i * HD_, bk + i * HD_, bv + i * HD_,
            qb, kb, vb);
        vtrans<<<1024, 256, 0, stream>>>(vb, vt);
        attn_mfma<<<512, 256, 0, stream>>>(qb, kb, vt, ob);
        // t1 = ob @ Wo + bo + hbuf   (64-row tile -> 512 blocks)
        gemm_mfma<64, false, true, true, false><<<dim3(E_ / 128, rows / 64), 256, 0, stream>>>(
            ob, wot + (size_t)i * E_ * E_, bo + i * E_, hbuf, t1, nullptr, rows, E_, E_);
        layernorm_k<true><<<rows, 256, 0, stream>>>(t1, g1 + i * E_, be1 + i * E_, hx, hxb);
        // ffb = relu(hx @ Wf1 + bf1)   (128-row tile, grid 1024)
        gemm_mfma<128, true, false, false, true><<<dim3(FF_ / 128, rows / 128), 256, 0, stream>>>(
            hxb, wf1t + (size_t)i * E_ * FF_, bf1 + i * FF_, nullptr, nullptr, ffb,
            rows, FF_, E_);
        // t1 = ffb @ Wf2 + bf2 + hx   (64-row tile -> 512 blocks)
        gemm_mfma<64, false, true, true, false><<<dim3(E_ / 128, rows / 64), 256, 0, stream>>>(
            ffb, wf2t + (size_t)i * FF_ * E_, bf2 + i * E_, hx, t1, nullptr,
            rows, E_, FF_);
        layernorm_k<true><<<rows, 256, 0, stream>>>(t1, g2 + i * E_, be2 + i * E_, hbuf, hb);
    }

    final_mfma<<<rows / 64, 256, 0, stream>>>(hb, wft, bfin, out);
}

// Round 10
// 1044.011 us; speedup vs baseline: 1.3403x; 1.0002x over previous
//
#include <hip/hip_runtime.h>
#include <hip/hip_bf16.h>
#include <math.h>

// Problem constants
#define N_ 8
#define S_ 1024
#define F_ 64
#define E_ 512
#define H_ 8
#define O_ 64
#define L_ 6
#define HD_ 64
#define FF_ 2048
#define SCALE_ 0.044194173824159216f   // 1/sqrt(E) -- module scales by sqrt(embed_size)
#define LOG2E_ 1.4426950408889634f
#define QSCALE_ (SCALE_ * LOG2E_)      // folded into Q at projection time

typedef unsigned short u16;
typedef __attribute__((ext_vector_type(8))) unsigned short u16x8;
typedef __attribute__((ext_vector_type(8))) short short8;
typedef __attribute__((ext_vector_type(4))) float floatx4;

__device__ __forceinline__ u16 f2b(float f) {          // RNE (weights, one-time)
    union { float f; unsigned u; } v; v.f = f;
    unsigned u = v.u;
    unsigned r = (u + 0x7FFFu + ((u >> 16) & 1u)) >> 16;
    return (u16)r;
}
__device__ __forceinline__ u16 f2b_fast(float f) {     // round-nearest, 2 ops
    union { float f; unsigned u; } v; v.f = f;
    return (u16)((v.u + 0x8000u) >> 16);
}
__device__ __forceinline__ float b2f(u16 h) {
    union { unsigned u; float f; } v; v.u = ((unsigned)h) << 16;
    return v.f;
}
// bijection on [0,16): spreads C-layout rows (4*quad+r) across all 32 banks
__device__ __forceinline__ int pperm(int row) {
    return ((2 * (row >> 2) + 5 * (row & 3)) & 7) | ((row & 2) << 2);
}

// ---------------------------------------------------------------------------
// MFMA first projection: h = relu(x^T W + b) + pos -> bf16 residual stream.
__global__ __launch_bounds__(256) void first_mfma(
    const float* __restrict__ x, const u16* __restrict__ wt,
    const float* __restrict__ bf, const float* __restrict__ pe,
    u16* __restrict__ resb)
{
    __shared__ u16 a_s[128][72];
    int t = threadIdx.x;
    int w = t >> 6, lane = t & 63, quad = lane >> 4, c16 = lane & 15;
    int rowhalf = w >> 1, colhalf = w & 1;
    int col0 = blockIdx.x * 128;
    int row0 = blockIdx.y * 128;          // n*S + s0 (never crosses n)
    int n = row0 >> 10, s0 = row0 & 1023;

    const float* xb = x + (size_t)n * F_ * S_ + s0;
    #pragma unroll
    for (int i = 0; i < 8; i++) {
        int pos = (t + i * 256) * 4;      // 8192 elems, f-major
        int f = pos >> 7, sl = pos & 127;
        float4 v = *(const float4*)&xb[(size_t)f * S_ + sl];
        a_s[sl + 0][f] = f2b_fast(v.x);
        a_s[sl + 1][f] = f2b_fast(v.y);
        a_s[sl + 2][f] = f2b_fast(v.z);
        a_s[sl + 3][f] = f2b_fast(v.w);
    }
    __syncthreads();

    floatx4 acc[4][4];
    #pragma unroll
    for (int mt = 0; mt < 4; mt++)
        #pragma unroll
        for (int nt = 0; nt < 4; nt++) acc[mt][nt] = (floatx4){0.f, 0.f, 0.f, 0.f};

    #pragma unroll
    for (int ks = 0; ks < 2; ks++) {
        short8 af[4], bfr[4];
        #pragma unroll
        for (int mt = 0; mt < 4; mt++)
            af[mt] = *(const short8*)&a_s[rowhalf * 64 + mt * 16 + c16][ks * 32 + quad * 8];
        #pragma unroll
        for (int nt = 0; nt < 4; nt++)
            bfr[nt] = *(const short8*)&wt[(size_t)(col0 + colhalf * 64 + nt * 16 + c16) * F_
                                          + ks * 32 + quad * 8];
        #pragma unroll
        for (int mt = 0; mt < 4; mt++)
            #pragma unroll
            for (int nt = 0; nt < 4; nt++)
                acc[mt][nt] = __builtin_amdgcn_mfma_f32_16x16x32_bf16(
                    af[mt], bfr[nt], acc[mt][nt], 0, 0, 0);
    }

    #pragma unroll
    for (int nt = 0; nt < 4; nt++) {
        int col = col0 + colhalf * 64 + nt * 16 + c16;
        float bv = bf[col];
        #pragma unroll
        for (int mt = 0; mt < 4; mt++) {
            #pragma unroll
            for (int r = 0; r < 4; r++) {
                size_t row = (size_t)row0 + rowhalf * 64 + mt * 16 + quad * 4 + r;
                int s = (int)(row & 1023);
                float v = fmaxf(acc[mt][nt][r] + bv, 0.f) + pe[(size_t)s * E_ + col];
                resb[row * E_ + col] = f2b_fast(v);
            }
        }
    }
}

// ---------------------------------------------------------------------------
// batched cast+transpose: W[K][Nc] fp32 -> Wt[Nc][K] bf16, per-layer stride.
__global__ __launch_bounds__(256) void wcast_t(
    const float* __restrict__ W0, u16* __restrict__ Wt0, int K, int Nc)
{
    __shared__ float tile[32][33];
    int t = threadIdx.x;
    int bx = blockIdx.x, by = blockIdx.y;
    const float* W = W0 + (size_t)blockIdx.z * K * Nc;
    u16* Wt = Wt0 + (size_t)blockIdx.z * K * Nc;
    #pragma unroll
    for (int i = 0; i < 4; i++) {
        int q = t + i * 256; int r = q >> 5, c = q & 31;
        tile[r][c] = W[(size_t)(by * 32 + r) * Nc + bx * 32 + c];
    }
    __syncthreads();
    #pragma unroll
    for (int i = 0; i < 4; i++) {
        int q = t + i * 256; int r = q >> 5, c = q & 31;
        Wt[(size_t)(bx * 32 + r) * K + by * 32 + c] = f2b(tile[c][r]);
    }
}

// ---------------------------------------------------------------------------
// batched cast+transpose of the three 64x64 qkv weights; block = layer
__global__ __launch_bounds__(256) void qkvw_cast(
    const float* __restrict__ Wq, const float* __restrict__ Wk,
    const float* __restrict__ Wv,
    u16* __restrict__ wqt, u16* __restrict__ wkt, u16* __restrict__ wvt)
{
    int l = blockIdx.x;
    int t = threadIdx.x;
    size_t off = (size_t)l * HD_ * HD_;
    #pragma unroll
    for (int i = 0; i < 16; i++) {
        int idx = t + i * 256;            // = e*64 + d
        int e = idx >> 6, d = idx & 63;
        wqt[off + idx] = f2b(Wq[off + d * HD_ + e]);
        wkt[off + idx] = f2b(Wk[off + d * HD_ + e]);
        wvt[off + idx] = f2b(Wv[off + d * HD_ + e]);
    }
}

// ---------------------------------------------------------------------------
// MFMA fused qkv; Q output pre-scaled by QSCALE_ (folded softmax scale+log2e)
__global__ __launch_bounds__(256) void qkv_mfma(
    const u16* __restrict__ hb,
    const u16* __restrict__ wqt, const u16* __restrict__ wkt,
    const u16* __restrict__ wvt,
    const float* __restrict__ bq, const float* __restrict__ bk,
    const float* __restrict__ bv,
    u16* __restrict__ qo, u16* __restrict__ ko, u16* __restrict__ vo)
{
    __shared__ u16 a_s[256][72];
    int t = threadIdx.x;
    int w = t >> 6, lane = t & 63, quad = lane >> 4, c16 = lane & 15;
    size_t row0 = (size_t)blockIdx.x * 256;

    #pragma unroll
    for (int i = 0; i < 8; i++) {
        int q = t + i * 256; int r = q >> 3, c = q & 7;
        *(u16x8*)&a_s[r][c * 8] = *(const u16x8*)&hb[(row0 + r) * HD_ + c * 8];
    }
    __syncthreads();

    short8 af[4][2];
    #pragma unroll
    for (int mt = 0; mt < 4; mt++)
        #pragma unroll
        for (int ks = 0; ks < 2; ks++)
            af[mt][ks] = *(const short8*)&a_s[w * 64 + mt * 16 + c16][ks * 32 + quad * 8];

    const u16* wts[3] = {wqt, wkt, wvt};
    const float* bs[3] = {bq, bk, bv};
    u16* outs[3] = {qo, ko, vo};

    #pragma unroll
    for (int m = 0; m < 3; m++) {
        short8 bfr[4][2];
        #pragma unroll
        for (int nt = 0; nt < 4; nt++)
            #pragma unroll
            for (int ks = 0; ks < 2; ks++)
                bfr[nt][ks] = *(const short8*)&wts[m][(nt * 16 + c16) * HD_ + ks * 32 + quad * 8];
        floatx4 acc[4][4];
        #pragma unroll
        for (int mt = 0; mt < 4; mt++)
            #pragma unroll
            for (int nt = 0; nt < 4; nt++) acc[mt][nt] = (floatx4){0.f, 0.f, 0.f, 0.f};
        #pragma unroll
        for (int ks = 0; ks < 2; ks++)
            #pragma unroll
            for (int mt = 0; mt < 4; mt++)
                #pragma unroll
                for (int nt = 0; nt < 4; nt++)
                    acc[mt][nt] = __builtin_amdgcn_mfma_f32_16x16x32_bf16(
                        af[mt][ks], bfr[nt][ks], acc[mt][nt], 0, 0, 0);
        float osc = (m == 0) ? QSCALE_ : 1.0f;
        #pragma unroll
        for (int nt = 0; nt < 4; nt++) {
            float bv_ = bs[m][nt * 16 + c16];
            #pragma unroll
            for (int mt = 0; mt < 4; mt++)
                #pragma unroll
                for (int r = 0; r < 4; r++)
                    outs[m][(row0 + w * 64 + mt * 16 + quad * 4 + r) * HD_ + nt * 16 + c16] =
                        f2b_fast((acc[mt][nt][r] + bv_) * osc);
        }
    }
}

// ---------------------------------------------------------------------------
// V transpose: vb (N,S,H,D) bf16 -> vt (N,H,D,S) bf16. grid N*H*(S/64)
__global__ __launch_bounds__(256) void vtrans(
    const u16* __restrict__ vb, u16* __restrict__ vt)
{
    int bid = blockIdx.x;
    int st = bid & 15, hh = (bid >> 4) & 7, n = bid >> 7;
    __shared__ u16 tile[64][72];
    int t = threadIdx.x;
    #pragma unroll
    for (int i = 0; i < 2; i++) {
        int q = t + i * 256; int sl = q >> 3, c = q & 7;
        *(u16x8*)&tile[sl][c * 8] =
            *(const u16x8*)&vb[(((size_t)(n * S_ + st * 64 + sl)) * H_ + hh) * 64 + c * 8];
    }
    __syncthreads();
    #pragma unroll
    for (int i = 0; i < 2; i++) {
        int q = t + i * 256; int d = q >> 3, sc = q & 7;
        u16x8 v;
        #pragma unroll
        for (int j = 0; j < 8; j++) v[j] = tile[sc * 8 + j][d];
        *(u16x8*)&vt[((size_t)(n * H_ + hh) * 64 + d) * (size_t)S_ + st * 64 + sc * 8] = v;
    }
}

// ---------------------------------------------------------------------------
// MFMA flash attention, no-max exp2 softmax (Q pre-scaled by QSCALE_).
// Block = (n, h, 64-query tile), grid 1024 (~4 blocks/CU); 4 waves x 16 q-rows.
// LDS 27.6 KB: P strips aliased onto Q tile (each wave reads/writes only its
// own 16-row strip; in-wave DS ordering makes the Q-read -> P-write safe).
__global__ __launch_bounds__(256, 2) void attn_mfma(
    const u16* __restrict__ Q, const u16* __restrict__ K,
    const u16* __restrict__ Vt, u16* __restrict__ O)
{
    int bid = blockIdx.x;            // N*H*(S/64) = 1024
    int qt = bid & 15, hh = (bid >> 4) & 7, n = bid >> 7;
    int t = threadIdx.x;
    int w = t >> 6, lane = t & 63, quad = lane >> 4, c16 = lane & 15;

    __shared__ u16 qp_s[64][72];     // Q tile, then per-wave 16-row P strips
    __shared__ u16 k_s[64][72];
    __shared__ u16 vt_s[64][72];
    u16 (*p_s)[72] = &qp_s[w * 16];  // wave-private strip

    const size_t qkbase = (size_t)n * S_ * E_ + hh * 64;
    const size_t vtbase = ((size_t)(n * H_ + hh) * 64) * (size_t)S_;

    #pragma unroll
    for (int i = 0; i < 2; i++) {
        int q = t + i * 256; int r = q >> 3, c = q & 7;
        *(u16x8*)&qp_s[r][c * 8] =
            *(const u16x8*)&Q[qkbase + (size_t)(qt * 64 + r) * E_ + c * 8];
    }
    __syncthreads();

    short8 af[2];                    // Q fragment for this wave's 16 rows
    #pragma unroll
    for (int ks = 0; ks < 2; ks++)
        af[ks] = *(const short8*)&qp_s[w * 16 + c16][ks * 32 + quad * 8];

    const short8 ones = {(short)0x3F80, (short)0x3F80, (short)0x3F80, (short)0x3F80,
                         (short)0x3F80, (short)0x3F80, (short)0x3F80, (short)0x3F80};
    const int pr = pperm(c16);
    int pw[4];
    #pragma unroll
    for (int r = 0; r < 4; r++) pw[r] = pperm(quad * 4 + r);

    floatx4 oacc[4], lacc;
    lacc = (floatx4){0.f, 0.f, 0.f, 0.f};
    #pragma unroll
    for (int nt = 0; nt < 4; nt++) oacc[nt] = (floatx4){0.f, 0.f, 0.f, 0.f};

    // register prefetch of K/V tiles
    int ar = t >> 3, acq = (t & 7) * 8;
    u16x8 pk[2], pv[2];
    #pragma unroll
    for (int i = 0; i < 2; i++) {
        pk[i] = *(const u16x8*)&K[qkbase + (size_t)(ar + i * 32) * E_ + acq];
        pv[i] = *(const u16x8*)&Vt[vtbase + (size_t)(ar + i * 32) * S_ + acq];
    }

    for (int k0 = 0; k0 < S_; k0 += 64) {
        #pragma unroll
        for (int i = 0; i < 2; i++) {
            *(u16x8*)&k_s[ar + i * 32][acq] = pk[i];
            *(u16x8*)&vt_s[ar + i * 32][acq] = pv[i];
        }
        __syncthreads();
        if (k0 + 64 < S_) {
            #pragma unroll
            for (int i = 0; i < 2; i++) {
                pk[i] = *(const u16x8*)&K[qkbase + (size_t)(k0 + 64 + ar + i * 32) * E_ + acq];
                pv[i] = *(const u16x8*)&Vt[vtbase + (size_t)(ar + i * 32) * S_ + k0 + 64 + acq];
            }
        }

        floatx4 sc[4];
        #pragma unroll
        for (int nt = 0; nt < 4; nt++) sc[nt] = (floatx4){0.f, 0.f, 0.f, 0.f};
        #pragma unroll
        for (int ks = 0; ks < 2; ks++) {
            short8 bfr[4];
            #pragma unroll
            for (int nt = 0; nt < 4; nt++)
                bfr[nt] = *(const short8*)&k_s[nt * 16 + c16][ks * 32 + quad * 8];
            #pragma unroll
            for (int nt = 0; nt < 4; nt++)
                sc[nt] = __builtin_amdgcn_mfma_f32_16x16x32_bf16(af[ks], bfr[nt], sc[nt], 0, 0, 0);
        }

        #pragma unroll
        for (int nt = 0; nt < 4; nt++)
            #pragma unroll
            for (int r = 0; r < 4; r++)
                p_s[pw[r]][nt * 16 + c16] = f2b_fast(exp2f(sc[nt][r]));

        #pragma unroll
        for (int ks = 0; ks < 2; ks++) {
            short8 vf[4];
            #pragma unroll
            for (int nt = 0; nt < 4; nt++)
                vf[nt] = *(const short8*)&vt_s[nt * 16 + c16][ks * 32 + quad * 8];
            short8 pf = *(const short8*)&p_s[pr][ks * 32 + quad * 8];
            lacc = __builtin_amdgcn_mfma_f32_16x16x32_bf16(pf, ones, lacc, 0, 0, 0);
            #pragma unroll
            for (int nt = 0; nt < 4; nt++)
                oacc[nt] = __builtin_amdgcn_mfma_f32_16x16x32_bf16(pf, vf[nt], oacc[nt], 0, 0, 0);
        }
        __syncthreads();
    }

    #pragma unroll
    for (int r = 0; r < 4; r++) {
        float rl = 1.f / lacc[r];
        int s = qt * 64 + w * 16 + quad * 4 + r;
        size_t base = (size_t)(n * S_ + s) * E_ + hh * 64;
        #pragma unroll
        for (int nt = 0; nt < 4; nt++)
            O[base + nt * 16 + c16] = f2b_fast(oacc[nt][r] * rl);
    }
}

// ---------------------------------------------------------------------------
// MFMA GEMM, software-pipelined staging; residual input is bf16.
template <int MT, bool RELU, bool HASRES, bool OUTF32, bool OUTBF16>
__global__ __launch_bounds__(256, 2) void gemm_mfma(
    const u16* __restrict__ A, const u16* __restrict__ Bt,
    const float* __restrict__ bias, const u16* __restrict__ resid,
    float* __restrict__ outf, u16* __restrict__ outb, int M, int Nc, int K)
{
    constexpr int MTILES = MT / 32;
    __shared__ u16 a_s[MT][72];
    __shared__ u16 b_s[128][72];
    int t = threadIdx.x;
    int w = t >> 6, lane = t & 63, quad = lane >> 4, c16 = lane & 15;
    int rowhalf = w >> 1, colhalf = w & 1;
    size_t row0 = (size_t)blockIdx.y * MT;
    size_t col0 = (size_t)blockIdx.x * 128;

    floatx4 acc[MTILES][4];
    #pragma unroll
    for (int mt = 0; mt < MTILES; mt++)
        #pragma unroll
        for (int nt = 0; nt < 4; nt++) acc[mt][nt] = (floatx4){0.f, 0.f, 0.f, 0.f};

    int ar = t >> 3, acq = (t & 7) * 8;
    u16x8 pa[MTILES], pb[4];
    #pragma unroll
    for (int i = 0; i < MTILES; i++)
        pa[i] = *(const u16x8*)&A[(row0 + ar + i * 32) * K + acq];
    #pragma unroll
    for (int i = 0; i < 4; i++)
        pb[i] = *(const u16x8*)&Bt[(col0 + ar + i * 32) * K + acq];

    for (int k0 = 0; k0 < K; k0 += 64) {
        #pragma unroll
        for (int i = 0; i < MTILES; i++)
            *(u16x8*)&a_s[ar + i * 32][acq] = pa[i];
        #pragma unroll
        for (int i = 0; i < 4; i++)
            *(u16x8*)&b_s[ar + i * 32][acq] = pb[i];
        __syncthreads();
        if (k0 + 64 < K) {
            #pragma unroll
            for (int i = 0; i < MTILES; i++)
                pa[i] = *(const u16x8*)&A[(row0 + ar + i * 32) * K + k0 + 64 + acq];
            #pragma unroll
            for (int i = 0; i < 4; i++)
                pb[i] = *(const u16x8*)&Bt[(col0 + ar + i * 32) * K + k0 + 64 + acq];
        }
        #pragma unroll
        for (int ks = 0; ks < 2; ks++) {
            short8 af[MTILES], bf[4];
            #pragma unroll
            for (int mt = 0; mt < MTILES; mt++)
                af[mt] = *(const short8*)&a_s[rowhalf * (MT / 2) + mt * 16 + c16][ks * 32 + quad * 8];
            #pragma unroll
            for (int nt = 0; nt < 4; nt++)
                bf[nt] = *(const short8*)&b_s[colhalf * 64 + nt * 16 + c16][ks * 32 + quad * 8];
            #pragma unroll
            for (int mt = 0; mt < MTILES; mt++)
                #pragma unroll
                for (int nt = 0; nt < 4; nt++)
                    acc[mt][nt] = __builtin_amdgcn_mfma_f32_16x16x32_bf16(
                        af[mt], bf[nt], acc[mt][nt], 0, 0, 0);
        }
        __syncthreads();
    }

    #pragma unroll
    for (int nt = 0; nt < 4; nt++) {
        int col = (int)col0 + colhalf * 64 + nt * 16 + c16;
        float bv = bias[col];
        #pragma unroll
        for (int mt = 0; mt < MTILES; mt++) {
            size_t rowb = row0 + rowhalf * (MT / 2) + mt * 16 + quad * 4;
            #pragma unroll
            for (int r = 0; r < 4; r++) {
                size_t row = rowb + r;
                float v = acc[mt][nt][r] + bv;
                if constexpr (HASRES) v += b2f(resid[row * Nc + col]);
                if constexpr (RELU) v = fmaxf(v, 0.f);
                if constexpr (OUTF32) outf[row * Nc + col] = v;
                if constexpr (OUTBF16) outb[row * Nc + col] = f2b_fast(v);
            }
        }
    }
}

// ---------------------------------------------------------------------------
// LayerNorm over E=512, one block per row; fp32 in, bf16 out.
__global__ __launch_bounds__(256) void layernorm_k(
    const float* __restrict__ in, const float* __restrict__ g,
    const float* __restrict__ bb, u16* __restrict__ outb)
{
    int row = blockIdx.x;
    int t = threadIdx.x;
    const float* x = in + (size_t)row * E_;
    float x0 = x[t], x1 = x[t + 256];
    float s = x0 + x1;
    #pragma unroll
    for (int off = 32; off; off >>= 1) s += __shfl_down(s, off, 64);
    __shared__ float red[4];
    int wid = t >> 6, lane = t & 63;
    if (lane == 0) red[wid] = s;
    __syncthreads();
    float m = (red[0] + red[1] + red[2] + red[3]) * (1.f / E_);
    float d0 = x0 - m, d1 = x1 - m;
    float sq = d0 * d0 + d1 * d1;
    #pragma unroll
    for (int off = 32; off; off >>= 1) sq += __shfl_down(sq, off, 64);
    __syncthreads();
    if (lane == 0) red[wid] = sq;
    __syncthreads();
    float var = (red[0] + red[1] + red[2] + red[3]) * (1.f / E_);
    float rstd = rsqrtf(var + 1e-5f);
    outb[(size_t)row * E_ + t] = f2b_fast(d0 * rstd * g[t] + bb[t]);
    outb[(size_t)row * E_ + t + 256] = f2b_fast(d1 * rstd * g[t + 256] + bb[t + 256]);
}

// ---------------------------------------------------------------------------
// MFMA final projection: out[n,o,s] = resb[n*S+s,:] @ Wfint[o,:] + bfin[o]
__global__ __launch_bounds__(256) void final_mfma(
    const u16* __restrict__ hb, const u16* __restrict__ wft,
    const float* __restrict__ bfin, float* __restrict__ outp)
{
    __shared__ u16 a_s[64][72];
    int t = threadIdx.x;
    int w = t >> 6, lane = t & 63, quad = lane >> 4, c16 = lane & 15;
    size_t row0 = (size_t)blockIdx.x * 64;

    floatx4 acc[4];
    #pragma unroll
    for (int nt = 0; nt < 4; nt++) acc[nt] = (floatx4){0.f, 0.f, 0.f, 0.f};

    int ar = t >> 3, acq = (t & 7) * 8;
    u16x8 pa[2];
    #pragma unroll
    for (int i = 0; i < 2; i++)
        pa[i] = *(const u16x8*)&hb[(row0 + ar + i * 32) * E_ + acq];

    for (int k0 = 0; k0 < E_; k0 += 64) {
        #pragma unroll
        for (int i = 0; i < 2; i++)
            *(u16x8*)&a_s[ar + i * 32][acq] = pa[i];
        __syncthreads();
        if (k0 + 64 < E_) {
            #pragma unroll
            for (int i = 0; i < 2; i++)
                pa[i] = *(const u16x8*)&hb[(row0 + ar + i * 32) * E_ + k0 + 64 + acq];
        }
        #pragma unroll
        for (int ks = 0; ks < 2; ks++) {
            short8 af = *(const short8*)&a_s[w * 16 + c16][ks * 32 + quad * 8];
            #pragma unroll
            for (int nt = 0; nt < 4; nt++) {
                short8 bf = *(const short8*)&wft[(nt * 16 + c16) * E_ + k0 + ks * 32 + quad * 8];
                acc[nt] = __builtin_amdgcn_mfma_f32_16x16x32_bf16(af, bf, acc[nt], 0, 0, 0);
            }
        }
        __syncthreads();
    }

    #pragma unroll
    for (int nt = 0; nt < 4; nt++) {
        int o = nt * 16 + c16;
        float bv = bfin[o];
        #pragma unroll
        for (int r = 0; r < 4; r++) {
            size_t row = row0 + w * 16 + quad * 4 + r;    // n*S + s
            int n = (int)(row >> 10), s = (int)(row & 1023);
            outp[((size_t)(n * O_ + o)) * S_ + s] = acc[nt][r] + bv;
        }
    }
}

// ---------------------------------------------------------------------------
extern "C" void kernel_launch(void* const* d_in, const int* in_sizes, int n_in,
                              void* d_out, int out_size, void* d_ws, size_t ws_size,
                              hipStream_t stream)
{
    const float* x       = (const float*)d_in[0];
    const float* W_first = (const float*)d_in[1];
    const float* b_first = (const float*)d_in[2];
    const float* pos_emb = (const float*)d_in[3];
    const float* Wq      = (const float*)d_in[4];
    const float* bq      = (const float*)d_in[5];
    const float* Wk      = (const float*)d_in[6];
    const float* bk      = (const float*)d_in[7];
    const float* Wv      = (const float*)d_in[8];
    const float* bv      = (const float*)d_in[9];
    const float* Wo      = (const float*)d_in[10];
    const float* bo      = (const float*)d_in[11];
    const float* g1      = (const float*)d_in[12];
    const float* be1     = (const float*)d_in[13];
    const float* Wf1     = (const float*)d_in[14];
    const float* bf1     = (const float*)d_in[15];
    const float* Wf2     = (const float*)d_in[16];
    const float* bf2     = (const float*)d_in[17];
    const float* g2      = (const float*)d_in[18];
    const float* be2     = (const float*)d_in[19];
    const float* Wfin    = (const float*)d_in[20];
    const float* bfin    = (const float*)d_in[21];
    float* out = (float*)d_out;

    const size_t M4 = (size_t)N_ * S_ * E_;       // 4,194,304
    float* t1   = (float*)d_ws;                   // fp32 LN input
    u16*   resb = (u16*)(t1 + M4);                // bf16 residual stream (h/hx)
    u16*   qb   = resb + M4;
    u16*   kb   = qb + M4;
    u16*   vb   = kb + M4;
    u16*   vt   = vb + M4;
    u16*   ob   = vt + M4;
    u16*   ffb  = qb;                             // alias qb..vt region
    u16*   wot  = ob + M4;                        // 6 * 512*512
    u16*   wf1t = wot + (size_t)L_ * E_ * E_;     // 6 * 2048*512 (as [FF][E])
    u16*   wf2t = wf1t + (size_t)L_ * E_ * FF_;   // 6 * 512*2048 (as [E][FF])
    u16*   wqt  = wf2t + (size_t)L_ * FF_ * E_;   // 6 * 64*64
    u16*   wkt  = wqt + (size_t)L_ * HD_ * HD_;
    u16*   wvt  = wkt + (size_t)L_ * HD_ * HD_;
    u16*   wft  = wvt + (size_t)L_ * HD_ * HD_;   // 64*512  (Wfin as [O][E])
    u16*   w1t  = wft + (size_t)O_ * E_;          // 512*64  (W_first as [E][F])

    const int rows = N_ * S_;                     // 8192

    qkvw_cast<<<L_, 256, 0, stream>>>(Wq, Wk, Wv, wqt, wkt, wvt);
    wcast_t<<<dim3(E_ / 32, F_ / 32, 1), 256, 0, stream>>>(W_first, w1t, F_, E_);
    wcast_t<<<dim3(E_ / 32, E_ / 32, L_), 256, 0, stream>>>(Wo, wot, E_, E_);
    wcast_t<<<dim3(FF_ / 32, E_ / 32, L_), 256, 0, stream>>>(Wf1, wf1t, E_, FF_);
    wcast_t<<<dim3(E_ / 32, FF_ / 32, L_), 256, 0, stream>>>(Wf2, wf2t, FF_, E_);
    wcast_t<<<dim3(O_ / 32, E_ / 32, 1), 256, 0, stream>>>(Wfin, wft, E_, O_);

    first_mfma<<<dim3(E_ / 128, rows / 128), 256, 0, stream>>>(
        x, w1t, b_first, pos_emb, resb);

    for (int i = 0; i < L_; i++) {
        qkv_mfma<<<256, 256, 0, stream>>>(
            resb, wqt + (size_t)i * HD_ * HD_, wkt + (size_t)i * HD_ * HD_,
            wvt + (size_t)i * HD_ * HD_, bq + i * HD_, bk + i * HD_, bv + i * HD_,
            qb, kb, vb);
        vtrans<<<1024, 256, 0, stream>>>(vb, vt);
        attn_mfma<<<1024, 256, 0, stream>>>(qb, kb, vt, ob);
        // t1 = ob @ Wo + bo + resb(h)
        gemm_mfma<64, false, true, true, false><<<dim3(E_ / 128, rows / 64), 256, 0, stream>>>(
            ob, wot + (size_t)i * E_ * E_, bo + i * E_, resb, t1, nullptr, rows, E_, E_);
        layernorm_k<<<rows, 256, 0, stream>>>(t1, g1 + i * E_, be1 + i * E_, resb);
        // ffb = relu(resb(hx) @ Wf1 + bf1)
        gemm_mfma<128, true, false, false, true><<<dim3(FF_ / 128, rows / 128), 256, 0, stream>>>(
            resb, wf1t + (size_t)i * E_ * FF_, bf1 + i * FF_, nullptr, nullptr, ffb,
            rows, FF_, E_);
        // t1 = ffb @ Wf2 + bf2 + resb(hx)
        gemm_mfma<64, false, true, true, false><<<dim3(E_ / 128, rows / 64), 256, 0, stream>>>(
            ffb, wf2t + (size_t)i * FF_ * E_, bf2 + i * E_, resb, t1, nullptr,
            rows, E_, FF_);
        layernorm_k<<<rows, 256, 0, stream>>>(t1, g2 + i * E_, be2 + i * E_, resb);
    }

    final_mfma<<<rows / 64, 256, 0, stream>>>(resb, wft, bfin, out);
}

// Round 11
// 1020.480 us; speedup vs baseline: 1.3712x; 1.0231x over previous
//
#include <hip/hip_runtime.h>
#include <hip/hip_bf16.h>
#include <math.h>

// Problem constants
#define N_ 8
#define S_ 1024
#define F_ 64
#define E_ 512
#define H_ 8
#define O_ 64
#define L_ 6
#define HD_ 64
#define FF_ 2048
#define SCALE_ 0.044194173824159216f   // 1/sqrt(E) -- module scales by sqrt(embed_size)
#define LOG2E_ 1.4426950408889634f
#define QSCALE_ (SCALE_ * LOG2E_)      // folded into Q at projection time

typedef unsigned short u16;
typedef __attribute__((ext_vector_type(4))) unsigned short u16x4;
typedef __attribute__((ext_vector_type(8))) unsigned short u16x8;
typedef __attribute__((ext_vector_type(8))) short short8;
typedef __attribute__((ext_vector_type(4))) float floatx4;

__device__ __forceinline__ u16 f2b(float f) {          // RNE (weights, one-time)
    union { float f; unsigned u; } v; v.f = f;
    unsigned u = v.u;
    unsigned r = (u + 0x7FFFu + ((u >> 16) & 1u)) >> 16;
    return (u16)r;
}
__device__ __forceinline__ u16 f2b_fast(float f) {     // round-nearest, 2 ops
    union { float f; unsigned u; } v; v.f = f;
    return (u16)((v.u + 0x8000u) >> 16);
}
__device__ __forceinline__ float b2f(u16 h) {
    union { unsigned u; float f; } v; v.u = ((unsigned)h) << 16;
    return v.f;
}

// ---------------------------------------------------------------------------
// MFMA first projection: h = relu(x^T W + b) + pos -> bf16 residual stream.
__global__ __launch_bounds__(256) void first_mfma(
    const float* __restrict__ x, const u16* __restrict__ wt,
    const float* __restrict__ bf, const float* __restrict__ pe,
    u16* __restrict__ resb)
{
    __shared__ u16 a_s[128][72];
    int t = threadIdx.x;
    int w = t >> 6, lane = t & 63, quad = lane >> 4, c16 = lane & 15;
    int rowhalf = w >> 1, colhalf = w & 1;
    int col0 = blockIdx.x * 128;
    int row0 = blockIdx.y * 128;          // n*S + s0 (never crosses n)
    int n = row0 >> 10, s0 = row0 & 1023;

    const float* xb = x + (size_t)n * F_ * S_ + s0;
    #pragma unroll
    for (int i = 0; i < 8; i++) {
        int pos = (t + i * 256) * 4;      // 8192 elems, f-major
        int f = pos >> 7, sl = pos & 127;
        float4 v = *(const float4*)&xb[(size_t)f * S_ + sl];
        a_s[sl + 0][f] = f2b_fast(v.x);
        a_s[sl + 1][f] = f2b_fast(v.y);
        a_s[sl + 2][f] = f2b_fast(v.z);
        a_s[sl + 3][f] = f2b_fast(v.w);
    }
    __syncthreads();

    floatx4 acc[4][4];
    #pragma unroll
    for (int mt = 0; mt < 4; mt++)
        #pragma unroll
        for (int nt = 0; nt < 4; nt++) acc[mt][nt] = (floatx4){0.f, 0.f, 0.f, 0.f};

    #pragma unroll
    for (int ks = 0; ks < 2; ks++) {
        short8 af[4], bfr[4];
        #pragma unroll
        for (int mt = 0; mt < 4; mt++)
            af[mt] = *(const short8*)&a_s[rowhalf * 64 + mt * 16 + c16][ks * 32 + quad * 8];
        #pragma unroll
        for (int nt = 0; nt < 4; nt++)
            bfr[nt] = *(const short8*)&wt[(size_t)(col0 + colhalf * 64 + nt * 16 + c16) * F_
                                          + ks * 32 + quad * 8];
        #pragma unroll
        for (int mt = 0; mt < 4; mt++)
            #pragma unroll
            for (int nt = 0; nt < 4; nt++)
                acc[mt][nt] = __builtin_amdgcn_mfma_f32_16x16x32_bf16(
                    af[mt], bfr[nt], acc[mt][nt], 0, 0, 0);
    }

    #pragma unroll
    for (int nt = 0; nt < 4; nt++) {
        int col = col0 + colhalf * 64 + nt * 16 + c16;
        float bv = bf[col];
        #pragma unroll
        for (int mt = 0; mt < 4; mt++) {
            #pragma unroll
            for (int r = 0; r < 4; r++) {
                size_t row = (size_t)row0 + rowhalf * 64 + mt * 16 + quad * 4 + r;
                int s = (int)(row & 1023);
                float v = fmaxf(acc[mt][nt][r] + bv, 0.f) + pe[(size_t)s * E_ + col];
                resb[row * E_ + col] = f2b_fast(v);
            }
        }
    }
}

// ---------------------------------------------------------------------------
// batched cast+transpose: W[K][Nc] fp32 -> Wt[Nc][K] bf16, per-layer stride.
__global__ __launch_bounds__(256) void wcast_t(
    const float* __restrict__ W0, u16* __restrict__ Wt0, int K, int Nc)
{
    __shared__ float tile[32][33];
    int t = threadIdx.x;
    int bx = blockIdx.x, by = blockIdx.y;
    const float* W = W0 + (size_t)blockIdx.z * K * Nc;
    u16* Wt = Wt0 + (size_t)blockIdx.z * K * Nc;
    #pragma unroll
    for (int i = 0; i < 4; i++) {
        int q = t + i * 256; int r = q >> 5, c = q & 31;
        tile[r][c] = W[(size_t)(by * 32 + r) * Nc + bx * 32 + c];
    }
    __syncthreads();
    #pragma unroll
    for (int i = 0; i < 4; i++) {
        int q = t + i * 256; int r = q >> 5, c = q & 31;
        Wt[(size_t)(bx * 32 + r) * K + by * 32 + c] = f2b(tile[c][r]);
    }
}

// ---------------------------------------------------------------------------
// batched cast+transpose of the three 64x64 qkv weights; block = layer
__global__ __launch_bounds__(256) void qkvw_cast(
    const float* __restrict__ Wq, const float* __restrict__ Wk,
    const float* __restrict__ Wv,
    u16* __restrict__ wqt, u16* __restrict__ wkt, u16* __restrict__ wvt)
{
    int l = blockIdx.x;
    int t = threadIdx.x;
    size_t off = (size_t)l * HD_ * HD_;
    #pragma unroll
    for (int i = 0; i < 16; i++) {
        int idx = t + i * 256;            // = e*64 + d
        int e = idx >> 6, d = idx & 63;
        wqt[off + idx] = f2b(Wq[off + d * HD_ + e]);
        wkt[off + idx] = f2b(Wk[off + d * HD_ + e]);
        wvt[off + idx] = f2b(Wv[off + d * HD_ + e]);
    }
}

// ---------------------------------------------------------------------------
// MFMA fused qkv; Q output pre-scaled by QSCALE_ (folded softmax scale+log2e)
__global__ __launch_bounds__(256) void qkv_mfma(
    const u16* __restrict__ hb,
    const u16* __restrict__ wqt, const u16* __restrict__ wkt,
    const u16* __restrict__ wvt,
    const float* __restrict__ bq, const float* __restrict__ bk,
    const float* __restrict__ bv,
    u16* __restrict__ qo, u16* __restrict__ ko, u16* __restrict__ vo)
{
    __shared__ u16 a_s[256][72];
    int t = threadIdx.x;
    int w = t >> 6, lane = t & 63, quad = lane >> 4, c16 = lane & 15;
    size_t row0 = (size_t)blockIdx.x * 256;

    #pragma unroll
    for (int i = 0; i < 8; i++) {
        int q = t + i * 256; int r = q >> 3, c = q & 7;
        *(u16x8*)&a_s[r][c * 8] = *(const u16x8*)&hb[(row0 + r) * HD_ + c * 8];
    }
    __syncthreads();

    short8 af[4][2];
    #pragma unroll
    for (int mt = 0; mt < 4; mt++)
        #pragma unroll
        for (int ks = 0; ks < 2; ks++)
            af[mt][ks] = *(const short8*)&a_s[w * 64 + mt * 16 + c16][ks * 32 + quad * 8];

    const u16* wts[3] = {wqt, wkt, wvt};
    const float* bs[3] = {bq, bk, bv};
    u16* outs[3] = {qo, ko, vo};

    #pragma unroll
    for (int m = 0; m < 3; m++) {
        short8 bfr[4][2];
        #pragma unroll
        for (int nt = 0; nt < 4; nt++)
            #pragma unroll
            for (int ks = 0; ks < 2; ks++)
                bfr[nt][ks] = *(const short8*)&wts[m][(nt * 16 + c16) * HD_ + ks * 32 + quad * 8];
        floatx4 acc[4][4];
        #pragma unroll
        for (int mt = 0; mt < 4; mt++)
            #pragma unroll
            for (int nt = 0; nt < 4; nt++) acc[mt][nt] = (floatx4){0.f, 0.f, 0.f, 0.f};
        #pragma unroll
        for (int ks = 0; ks < 2; ks++)
            #pragma unroll
            for (int mt = 0; mt < 4; mt++)
                #pragma unroll
                for (int nt = 0; nt < 4; nt++)
                    acc[mt][nt] = __builtin_amdgcn_mfma_f32_16x16x32_bf16(
                        af[mt][ks], bfr[nt][ks], acc[mt][nt], 0, 0, 0);
        float osc = (m == 0) ? QSCALE_ : 1.0f;
        #pragma unroll
        for (int nt = 0; nt < 4; nt++) {
            float bv_ = bs[m][nt * 16 + c16];
            #pragma unroll
            for (int mt = 0; mt < 4; mt++)
                #pragma unroll
                for (int r = 0; r < 4; r++)
                    outs[m][(row0 + w * 64 + mt * 16 + quad * 4 + r) * HD_ + nt * 16 + c16] =
                        f2b_fast((acc[mt][nt][r] + bv_) * osc);
        }
    }
}

// ---------------------------------------------------------------------------
// V transpose: vb (N,S,H,D) bf16 -> vt (N,H,D,S) bf16. grid N*H*(S/64)
__global__ __launch_bounds__(256) void vtrans(
    const u16* __restrict__ vb, u16* __restrict__ vt)
{
    int bid = blockIdx.x;
    int st = bid & 15, hh = (bid >> 4) & 7, n = bid >> 7;
    __shared__ u16 tile[64][72];
    int t = threadIdx.x;
    #pragma unroll
    for (int i = 0; i < 2; i++) {
        int q = t + i * 256; int sl = q >> 3, c = q & 7;
        *(u16x8*)&tile[sl][c * 8] =
            *(const u16x8*)&vb[(((size_t)(n * S_ + st * 64 + sl)) * H_ + hh) * 64 + c * 8];
    }
    __syncthreads();
    #pragma unroll
    for (int i = 0; i < 2; i++) {
        int q = t + i * 256; int d = q >> 3, sc = q & 7;
        u16x8 v;
        #pragma unroll
        for (int j = 0; j < 8; j++) v[j] = tile[sc * 8 + j][d];
        *(u16x8*)&vt[((size_t)(n * H_ + hh) * 64 + d) * (size_t)S_ + st * 64 + sc * 8] = v;
    }
}

// ---------------------------------------------------------------------------
// MFMA flash attention, transposed dataflow: S^T = K Q^T (P exits with 4
// contiguous keys per lane -> b64 packed LDS writes), O^T = V^T P^T (4
// contiguous d per lane -> 8B global stores). No-max exp2 softmax.
// Block = (n, h, 128-query tile), grid 512; LDS 36.9 KB (P aliased onto Q).
__global__ __launch_bounds__(256, 2) void attn_mfma(
    const u16* __restrict__ Q, const u16* __restrict__ K,
    const u16* __restrict__ Vt, u16* __restrict__ O)
{
    int bid = blockIdx.x;            // N*H*(S/128) = 512
    int qt = bid & 7, hh = (bid >> 3) & 7, n = bid >> 6;
    int t = threadIdx.x;
    int w = t >> 6, lane = t & 63, quad = lane >> 4, c16 = lane & 15;

    __shared__ u16 qp_s[128][72];    // Q tile, then per-wave 32-row P strips
    __shared__ u16 k_s[64][72];      // K rows (key, d)
    __shared__ u16 vt_s[64][72];     // Vt rows (d, key)
    u16 (*p_s)[72] = &qp_s[w * 32];  // wave-private strip, [q_local][key]

    const size_t qkbase = (size_t)n * S_ * E_ + hh * 64;
    const size_t vtbase = ((size_t)(n * H_ + hh) * 64) * (size_t)S_;

    #pragma unroll
    for (int i = 0; i < 4; i++) {
        int q = t + i * 256; int r = q >> 3, c = q & 7;
        *(u16x8*)&qp_s[r][c * 8] =
            *(const u16x8*)&Q[qkbase + (size_t)(qt * 128 + r) * E_ + c * 8];
    }
    __syncthreads();

    // hoist Q fragments (B-operand of S^T): q rows w*32 + nq*16 + c16
    short8 qf[2][2];
    #pragma unroll
    for (int nq = 0; nq < 2; nq++)
        #pragma unroll
        for (int ks = 0; ks < 2; ks++)
            qf[nq][ks] = *(const short8*)&qp_s[w * 32 + nq * 16 + c16][ks * 32 + quad * 8];

    const short8 ones = {(short)0x3F80, (short)0x3F80, (short)0x3F80, (short)0x3F80,
                         (short)0x3F80, (short)0x3F80, (short)0x3F80, (short)0x3F80};

    floatx4 oaccT[4][2];             // [d-tile][q-tile]: O^T[d][q]
    floatx4 lacc[2];
    #pragma unroll
    for (int nq = 0; nq < 2; nq++) {
        lacc[nq] = (floatx4){0.f, 0.f, 0.f, 0.f};
        #pragma unroll
        for (int mt = 0; mt < 4; mt++) oaccT[mt][nq] = (floatx4){0.f, 0.f, 0.f, 0.f};
    }

    // register prefetch of K/V tiles
    int ar = t >> 3, acq = (t & 7) * 8;
    u16x8 pk[2], pv[2];
    #pragma unroll
    for (int i = 0; i < 2; i++) {
        pk[i] = *(const u16x8*)&K[qkbase + (size_t)(ar + i * 32) * E_ + acq];
        pv[i] = *(const u16x8*)&Vt[vtbase + (size_t)(ar + i * 32) * S_ + acq];
    }

    for (int k0 = 0; k0 < S_; k0 += 64) {
        #pragma unroll
        for (int i = 0; i < 2; i++) {
            *(u16x8*)&k_s[ar + i * 32][acq] = pk[i];
            *(u16x8*)&vt_s[ar + i * 32][acq] = pv[i];
        }
        __syncthreads();
        if (k0 + 64 < S_) {
            #pragma unroll
            for (int i = 0; i < 2; i++) {
                pk[i] = *(const u16x8*)&K[qkbase + (size_t)(k0 + 64 + ar + i * 32) * E_ + acq];
                pv[i] = *(const u16x8*)&Vt[vtbase + (size_t)(ar + i * 32) * S_ + k0 + 64 + acq];
            }
        }

        // S^T = K Q^T : st[mt][nq], lane holds S[q=c16][key=mt*16+quad*4+r]
        floatx4 st[4][2];
        #pragma unroll
        for (int mt = 0; mt < 4; mt++)
            #pragma unroll
            for (int nq = 0; nq < 2; nq++) st[mt][nq] = (floatx4){0.f, 0.f, 0.f, 0.f};
        #pragma unroll
        for (int ks = 0; ks < 2; ks++) {
            short8 kf[4];
            #pragma unroll
            for (int mt = 0; mt < 4; mt++)
                kf[mt] = *(const short8*)&k_s[mt * 16 + c16][ks * 32 + quad * 8];
            #pragma unroll
            for (int mt = 0; mt < 4; mt++)
                #pragma unroll
                for (int nq = 0; nq < 2; nq++)
                    st[mt][nq] = __builtin_amdgcn_mfma_f32_16x16x32_bf16(
                        kf[mt], qf[nq][ks], st[mt][nq], 0, 0, 0);
        }

        // P = exp2(S^T), pack 4 keys -> one b64 LDS write per (nq,mt)
        #pragma unroll
        for (int nq = 0; nq < 2; nq++)
            #pragma unroll
            for (int mt = 0; mt < 4; mt++) {
                u16x4 h;
                #pragma unroll
                for (int r = 0; r < 4; r++) h[r] = f2b_fast(exp2f(st[mt][nq][r]));
                *(u16x4*)&p_s[nq * 16 + c16][mt * 16 + quad * 4] = h;
            }

        // O^T += V^T P^T ; l += ones . P^T
        #pragma unroll
        for (int ks = 0; ks < 2; ks++) {
            short8 pf[2];
            #pragma unroll
            for (int nq = 0; nq < 2; nq++)
                pf[nq] = *(const short8*)&p_s[nq * 16 + c16][ks * 32 + quad * 8];
            short8 vf[4];
            #pragma unroll
            for (int mt = 0; mt < 4; mt++)
                vf[mt] = *(const short8*)&vt_s[mt * 16 + c16][ks * 32 + quad * 8];
            #pragma unroll
            for (int nq = 0; nq < 2; nq++) {
                lacc[nq] = __builtin_amdgcn_mfma_f32_16x16x32_bf16(ones, pf[nq], lacc[nq], 0, 0, 0);
                #pragma unroll
                for (int mt = 0; mt < 4; mt++)
                    oaccT[mt][nq] = __builtin_amdgcn_mfma_f32_16x16x32_bf16(
                        vf[mt], pf[nq], oaccT[mt][nq], 0, 0, 0);
            }
        }
        __syncthreads();
    }

    // epilogue: lane c16 owns q-row; 4 contiguous d per (mt) -> 8B stores
    #pragma unroll
    for (int nq = 0; nq < 2; nq++) {
        float rl = 1.f / lacc[nq][0];
        int s = qt * 128 + w * 32 + nq * 16 + c16;
        size_t base = (size_t)(n * S_ + s) * E_ + hh * 64;
        #pragma unroll
        for (int mt = 0; mt < 4; mt++) {
            u16x4 h;
            #pragma unroll
            for (int r = 0; r < 4; r++) h[r] = f2b_fast(oaccT[mt][nq][r] * rl);
            *(u16x4*)&O[base + mt * 16 + quad * 4] = h;
        }
    }
}

// ---------------------------------------------------------------------------
// MFMA GEMM, software-pipelined staging; residual input is bf16.
template <int MT, bool RELU, bool HASRES, bool OUTF32, bool OUTBF16>
__global__ __launch_bounds__(256, 2) void gemm_mfma(
    const u16* __restrict__ A, const u16* __restrict__ Bt,
    const float* __restrict__ bias, const u16* __restrict__ resid,
    float* __restrict__ outf, u16* __restrict__ outb, int M, int Nc, int K)
{
    constexpr int MTILES = MT / 32;
    __shared__ u16 a_s[MT][72];
    __shared__ u16 b_s[128][72];
    int t = threadIdx.x;
    int w = t >> 6, lane = t & 63, quad = lane >> 4, c16 = lane & 15;
    int rowhalf = w >> 1, colhalf = w & 1;
    size_t row0 = (size_t)blockIdx.y * MT;
    size_t col0 = (size_t)blockIdx.x * 128;

    floatx4 acc[MTILES][4];
    #pragma unroll
    for (int mt = 0; mt < MTILES; mt++)
        #pragma unroll
        for (int nt = 0; nt < 4; nt++) acc[mt][nt] = (floatx4){0.f, 0.f, 0.f, 0.f};

    int ar = t >> 3, acq = (t & 7) * 8;
    u16x8 pa[MTILES], pb[4];
    #pragma unroll
    for (int i = 0; i < MTILES; i++)
        pa[i] = *(const u16x8*)&A[(row0 + ar + i * 32) * K + acq];
    #pragma unroll
    for (int i = 0; i < 4; i++)
        pb[i] = *(const u16x8*)&Bt[(col0 + ar + i * 32) * K + acq];

    for (int k0 = 0; k0 < K; k0 += 64) {
        #pragma unroll
        for (int i = 0; i < MTILES; i++)
            *(u16x8*)&a_s[ar + i * 32][acq] = pa[i];
        #pragma unroll
        for (int i = 0; i < 4; i++)
            *(u16x8*)&b_s[ar + i * 32][acq] = pb[i];
        __syncthreads();
        if (k0 + 64 < K) {
            #pragma unroll
            for (int i = 0; i < MTILES; i++)
                pa[i] = *(const u16x8*)&A[(row0 + ar + i * 32) * K + k0 + 64 + acq];
            #pragma unroll
            for (int i = 0; i < 4; i++)
                pb[i] = *(const u16x8*)&Bt[(col0 + ar + i * 32) * K + k0 + 64 + acq];
        }
        #pragma unroll
        for (int ks = 0; ks < 2; ks++) {
            short8 af[MTILES], bf[4];
            #pragma unroll
            for (int mt = 0; mt < MTILES; mt++)
                af[mt] = *(const short8*)&a_s[rowhalf * (MT / 2) + mt * 16 + c16][ks * 32 + quad * 8];
            #pragma unroll
            for (int nt = 0; nt < 4; nt++)
                bf[nt] = *(const short8*)&b_s[colhalf * 64 + nt * 16 + c16][ks * 32 + quad * 8];
            #pragma unroll
            for (int mt = 0; mt < MTILES; mt++)
                #pragma unroll
                for (int nt = 0; nt < 4; nt++)
                    acc[mt][nt] = __builtin_amdgcn_mfma_f32_16x16x32_bf16(
                        af[mt], bf[nt], acc[mt][nt], 0, 0, 0);
        }
        __syncthreads();
    }

    #pragma unroll
    for (int nt = 0; nt < 4; nt++) {
        int col = (int)col0 + colhalf * 64 + nt * 16 + c16;
        float bv = bias[col];
        #pragma unroll
        for (int mt = 0; mt < MTILES; mt++) {
            size_t rowb = row0 + rowhalf * (MT / 2) + mt * 16 + quad * 4;
            #pragma unroll
            for (int r = 0; r < 4; r++) {
                size_t row = rowb + r;
                float v = acc[mt][nt][r] + bv;
                if constexpr (HASRES) v += b2f(resid[row * Nc + col]);
                if constexpr (RELU) v = fmaxf(v, 0.f);
                if constexpr (OUTF32) outf[row * Nc + col] = v;
                if constexpr (OUTBF16) outb[row * Nc + col] = f2b_fast(v);
            }
        }
    }
}

// ---------------------------------------------------------------------------
// LayerNorm over E=512, one block per row; fp32 in, bf16 out.
__global__ __launch_bounds__(256) void layernorm_k(
    const float* __restrict__ in, const float* __restrict__ g,
    const float* __restrict__ bb, u16* __restrict__ outb)
{
    int row = blockIdx.x;
    int t = threadIdx.x;
    const float* x = in + (size_t)row * E_;
    float x0 = x[t], x1 = x[t + 256];
    float s = x0 + x1;
    #pragma unroll
    for (int off = 32; off; off >>= 1) s += __shfl_down(s, off, 64);
    __shared__ float red[4];
    int wid = t >> 6, lane = t & 63;
    if (lane == 0) red[wid] = s;
    __syncthreads();
    float m = (red[0] + red[1] + red[2] + red[3]) * (1.f / E_);
    float d0 = x0 - m, d1 = x1 - m;
    float sq = d0 * d0 + d1 * d1;
    #pragma unroll
    for (int off = 32; off; off >>= 1) sq += __shfl_down(sq, off, 64);
    __syncthreads();
    if (lane == 0) red[wid] = sq;
    __syncthreads();
    float var = (red[0] + red[1] + red[2] + red[3]) * (1.f / E_);
    float rstd = rsqrtf(var + 1e-5f);
    outb[(size_t)row * E_ + t] = f2b_fast(d0 * rstd * g[t] + bb[t]);
    outb[(size_t)row * E_ + t + 256] = f2b_fast(d1 * rstd * g[t + 256] + bb[t + 256]);
}

// ---------------------------------------------------------------------------
// MFMA final projection: out[n,o,s] = resb[n*S+s,:] @ Wfint[o,:] + bfin[o]
__global__ __launch_bounds__(256) void final_mfma(
    const u16* __restrict__ hb, const u16* __restrict__ wft,
    const float* __restrict__ bfin, float* __restrict__ outp)
{
    __shared__ u16 a_s[64][72];
    int t = threadIdx.x;
    int w = t >> 6, lane = t & 63, quad = lane >> 4, c16 = lane & 15;
    size_t row0 = (size_t)blockIdx.x * 64;

    floatx4 acc[4];
    #pragma unroll
    for (int nt = 0; nt < 4; nt++) acc[nt] = (floatx4){0.f, 0.f, 0.f, 0.f};

    int ar = t >> 3, acq = (t & 7) * 8;
    u16x8 pa[2];
    #pragma unroll
    for (int i = 0; i < 2; i++)
        pa[i] = *(const u16x8*)&hb[(row0 + ar + i * 32) * E_ + acq];

    for (int k0 = 0; k0 < E_; k0 += 64) {
        #pragma unroll
        for (int i = 0; i < 2; i++)
            *(u16x8*)&a_s[ar + i * 32][acq] = pa[i];
        __syncthreads();
        if (k0 + 64 < E_) {
            #pragma unroll
            for (int i = 0; i < 2; i++)
                pa[i] = *(const u16x8*)&hb[(row0 + ar + i * 32) * E_ + k0 + 64 + acq];
        }
        #pragma unroll
        for (int ks = 0; ks < 2; ks++) {
            short8 af = *(const short8*)&a_s[w * 16 + c16][ks * 32 + quad * 8];
            #pragma unroll
            for (int nt = 0; nt < 4; nt++) {
                short8 bf = *(const short8*)&wft[(nt * 16 + c16) * E_ + k0 + ks * 32 + quad * 8];
                acc[nt] = __builtin_amdgcn_mfma_f32_16x16x32_bf16(af, bf, acc[nt], 0, 0, 0);
            }
        }
        __syncthreads();
    }

    #pragma unroll
    for (int nt = 0; nt < 4; nt++) {
        int o = nt * 16 + c16;
        float bv = bfin[o];
        #pragma unroll
        for (int r = 0; r < 4; r++) {
            size_t row = row0 + w * 16 + quad * 4 + r;    // n*S + s
            int n = (int)(row >> 10), s = (int)(row & 1023);
            outp[((size_t)(n * O_ + o)) * S_ + s] = acc[nt][r] + bv;
        }
    }
}

// ---------------------------------------------------------------------------
extern "C" void kernel_launch(void* const* d_in, const int* in_sizes, int n_in,
                              void* d_out, int out_size, void* d_ws, size_t ws_size,
                              hipStream_t stream)
{
    const float* x       = (const float*)d_in[0];
    const float* W_first = (const float*)d_in[1];
    const float* b_first = (const float*)d_in[2];
    const float* pos_emb = (const float*)d_in[3];
    const float* Wq      = (const float*)d_in[4];
    const float* bq      = (const float*)d_in[5];
    const float* Wk      = (const float*)d_in[6];
    const float* bk      = (const float*)d_in[7];
    const float* Wv      = (const float*)d_in[8];
    const float* bv      = (const float*)d_in[9];
    const float* Wo      = (const float*)d_in[10];
    const float* bo      = (const float*)d_in[11];
    const float* g1      = (const float*)d_in[12];
    const float* be1     = (const float*)d_in[13];
    const float* Wf1     = (const float*)d_in[14];
    const float* bf1     = (const float*)d_in[15];
    const float* Wf2     = (const float*)d_in[16];
    const float* bf2     = (const float*)d_in[17];
    const float* g2      = (const float*)d_in[18];
    const float* be2     = (const float*)d_in[19];
    const float* Wfin    = (const float*)d_in[20];
    const float* bfin    = (const float*)d_in[21];
    float* out = (float*)d_out;

    const size_t M4 = (size_t)N_ * S_ * E_;       // 4,194,304
    float* t1   = (float*)d_ws;                   // fp32 LN input
    u16*   resb = (u16*)(t1 + M4);                // bf16 residual stream (h/hx)
    u16*   qb   = resb + M4;
    u16*   kb   = qb + M4;
    u16*   vb   = kb + M4;
    u16*   vt   = vb + M4;
    u16*   ob   = vt + M4;
    u16*   ffb  = qb;                             // alias qb..vt region
    u16*   wot  = ob + M4;                        // 6 * 512*512
    u16*   wf1t = wot + (size_t)L_ * E_ * E_;     // 6 * 2048*512 (as [FF][E])
    u16*   wf2t = wf1t + (size_t)L_ * E_ * FF_;   // 6 * 512*2048 (as [E][FF])
    u16*   wqt  = wf2t + (size_t)L_ * FF_ * E_;   // 6 * 64*64
    u16*   wkt  = wqt + (size_t)L_ * HD_ * HD_;
    u16*   wvt  = wkt + (size_t)L_ * HD_ * HD_;
    u16*   wft  = wvt + (size_t)L_ * HD_ * HD_;   // 64*512  (Wfin as [O][E])
    u16*   w1t  = wft + (size_t)O_ * E_;          // 512*64  (W_first as [E][F])

    const int rows = N_ * S_;                     // 8192

    qkvw_cast<<<L_, 256, 0, stream>>>(Wq, Wk, Wv, wqt, wkt, wvt);
    wcast_t<<<dim3(E_ / 32, F_ / 32, 1), 256, 0, stream>>>(W_first, w1t, F_, E_);
    wcast_t<<<dim3(E_ / 32, E_ / 32, L_), 256, 0, stream>>>(Wo, wot, E_, E_);
    wcast_t<<<dim3(FF_ / 32, E_ / 32, L_), 256, 0, stream>>>(Wf1, wf1t, E_, FF_);
    wcast_t<<<dim3(E_ / 32, FF_ / 32, L_), 256, 0, stream>>>(Wf2, wf2t, FF_, E_);
    wcast_t<<<dim3(O_ / 32, E_ / 32, 1), 256, 0, stream>>>(Wfin, wft, E_, O_);

    first_mfma<<<dim3(E_ / 128, rows / 128), 256, 0, stream>>>(
        x, w1t, b_first, pos_emb, resb);

    for (int i = 0; i < L_; i++) {
        qkv_mfma<<<256, 256, 0, stream>>>(
            resb, wqt + (size_t)i * HD_ * HD_, wkt + (size_t)i * HD_ * HD_,
            wvt + (size_t)i * HD_ * HD_, bq + i * HD_, bk + i * HD_, bv + i * HD_,
            qb, kb, vb);
        vtrans<<<1024, 256, 0, stream>>>(vb, vt);
        attn_mfma<<<512, 256, 0, stream>>>(qb, kb, vt, ob);
        // t1 = ob @ Wo + bo + resb(h)
        gemm_mfma<64, false, true, true, false><<<dim3(E_ / 128, rows / 64), 256, 0, stream>>>(
            ob, wot + (size_t)i * E_ * E_, bo + i * E_, resb, t1, nullptr, rows, E_, E_);
        layernorm_k<<<rows, 256, 0, stream>>>(t1, g1 + i * E_, be1 + i * E_, resb);
        // ffb = relu(resb(hx) @ Wf1 + bf1)
        gemm_mfma<128, true, false, false, true><<<dim3(FF_ / 128, rows / 128), 256, 0, stream>>>(
            resb, wf1t + (size_t)i * E_ * FF_, bf1 + i * FF_, nullptr, nullptr, ffb,
            rows, FF_, E_);
        // t1 = ffb @ Wf2 + bf2 + resb(hx)
        gemm_mfma<64, false, true, true, false><<<dim3(E_ / 128, rows / 64), 256, 0, stream>>>(
            ffb, wf2t + (size_t)i * FF_ * E_, bf2 + i * E_, resb, t1, nullptr,
            rows, E_, FF_);
        layernorm_k<<<rows, 256, 0, stream>>>(t1, g2 + i * E_, be2 + i * E_, resb);
    }

    final_mfma<<<rows / 64, 256, 0, stream>>>(resb, wft, bfin, out);
}